// Round 1
// baseline (1218.381 us; speedup 1.0000x reference)
//
#include <hip/hip_runtime.h>
#include <hip/hip_bf16.h>

// ---------------------------------------------------------------------------
// 3-layer GAT (PyG GATConv style) on MI355X.
// Strategy: build dst-grouped CSR once per call (no float atomics), then per
// layer: GEMM (h = x@W), per-node logits (a_src/a_dst), and a wave-per-node
// edge-softmax + aggregate with online max/sum. All fp32.
// ---------------------------------------------------------------------------

__device__ __forceinline__ float lrelu(float x) { return x > 0.f ? x : 0.2f * x; }

// ---- CSR build ------------------------------------------------------------
__global__ void count_deg(const int* __restrict__ edges, int E, int n,
                          int* __restrict__ deg) {
    int e = blockIdx.x * blockDim.x + threadIdx.x;
    int EP = E + n;
    if (e >= EP) return;
    int d = (e < E) ? edges[E + e] : (e - E);   // self-loop appended
    atomicAdd(&deg[d], 1);
}

__global__ void scan_rowptr(const int* __restrict__ deg, int* __restrict__ row_ptr,
                            int* __restrict__ cursor, int n) {
    __shared__ int buf[1024];
    __shared__ int carry;
    int tid = threadIdx.x;
    if (tid == 0) carry = 0;
    __syncthreads();
    for (int base = 0; base < n; base += 1024) {
        int i = base + tid;
        int v = (i < n) ? deg[i] : 0;
        buf[tid] = v;
        __syncthreads();
        for (int off = 1; off < 1024; off <<= 1) {
            int t = (tid >= off) ? buf[tid - off] : 0;
            __syncthreads();
            buf[tid] += t;
            __syncthreads();
        }
        int excl = carry + buf[tid] - v;
        if (i < n) { row_ptr[i] = excl; cursor[i] = excl; }
        __syncthreads();                       // all carry reads done
        if (tid == 1023) carry += buf[1023];
        __syncthreads();
    }
    if (tid == 0) row_ptr[n] = carry;
}

__global__ void scatter_edges(const int* __restrict__ edges, int E, int n,
                              int* __restrict__ cursor, int* __restrict__ ssrc) {
    int e = blockIdx.x * blockDim.x + threadIdx.x;
    int EP = E + n;
    if (e >= EP) return;
    int s, d;
    if (e < E) { s = edges[e]; d = edges[E + e]; }
    else       { s = e - E;    d = e - E; }
    int p = atomicAdd(&cursor[d], 1);
    ssrc[p] = s;
}

// ---- h = X @ W  (X: n x 64, W: 64 x OUT) ----------------------------------
template <int OUT>
__global__ __launch_bounds__(256) void gemm64(const float* __restrict__ X,
                                              const float* __restrict__ W,
                                              float* __restrict__ Hout, int n) {
    __shared__ float xs[64][64];
    __shared__ float ws[64][OUT];
    int tid = threadIdx.x;
    int row0 = blockIdx.x * 64;
    for (int i = tid; i < 64 * OUT / 4; i += 256)
        ((float4*)&ws[0][0])[i] = ((const float4*)W)[i];
    for (int i = tid; i < 64 * 64 / 4; i += 256) {
        int r = (i * 4) / 64, c = (i * 4) % 64;
        int gr = row0 + r;
        float4 v = make_float4(0.f, 0.f, 0.f, 0.f);
        if (gr < n) v = ((const float4*)(X + (size_t)gr * 64))[c / 4];
        ((float4*)&xs[0][0])[i] = v;
    }
    __syncthreads();
    const int c = tid % OUT;
    const int RSTEP = 256 / OUT;
    for (int r = tid / OUT; r < 64; r += RSTEP) {
        int gr = row0 + r;
        if (gr >= n) break;
        float acc = 0.f;
#pragma unroll
        for (int k = 0; k < 64; k++) acc += xs[r][k] * ws[k][c];
        Hout[(size_t)gr * OUT + c] = acc;
    }
}

// ---- per-node attention logits -------------------------------------------
template <int H, int C>
__global__ void att_logits(const float* __restrict__ Hf, const float* __restrict__ att_s,
                           const float* __restrict__ att_d, float* __restrict__ a_src,
                           float* __restrict__ a_dst, int n) {
    int idx = blockIdx.x * blockDim.x + threadIdx.x;
    if (idx >= n * H) return;
    int node = idx / H, h = idx % H;
    const float* hp = Hf + (size_t)node * H * C + h * C;
    float ss = 0.f, sd = 0.f;
#pragma unroll
    for (int c = 0; c < C; c++) {
        float v = hp[c];
        ss += v * att_s[h * C + c];
        sd += v * att_d[h * C + c];
    }
    a_src[idx] = ss;
    a_dst[idx] = sd;
}

// ---- wave-per-node softmax + aggregate (+bias, +optional ELU) -------------
template <int H, int C, bool DO_ELU>
__global__ __launch_bounds__(256) void aggregate(
    const int* __restrict__ row_ptr, const int* __restrict__ ssrc,
    const float* __restrict__ Hf, const float* __restrict__ a_src,
    const float* __restrict__ a_dst, const float* __restrict__ bias,
    float* __restrict__ Xout, int n) {
    int wid = (blockIdx.x * blockDim.x + threadIdx.x) >> 6;
    if (wid >= n) return;
    int lane = threadIdx.x & 63;
    constexpr int HC = H * C;
    int head = (lane / C) % H;
    int start = row_ptr[wid], end = row_ptr[wid + 1];
    float adst = a_dst[wid * H + head];

    // online max + sum of exp
    float m = -1e30f, ssum = 0.f;
    for (int e = start; e < end; e++) {
        int s = ssrc[e];
        float ev = lrelu(a_src[s * H + head] + adst);
        if (ev <= m) ssum += __expf(ev - m);
        else { ssum = ssum * __expf(m - ev) + 1.f; m = ev; }
    }
    float inv = 1.f / (ssum + 1e-16f);

    float acc = 0.f;
    int ch = lane % HC;
    for (int e = start; e < end; e++) {
        int s = ssrc[e];
        float ev = lrelu(a_src[s * H + head] + adst);
        float alpha = __expf(ev - m) * inv;
        acc += alpha * Hf[(size_t)s * HC + ch];
    }
    if (lane < HC) {
        float v = acc + bias[lane];
        if (DO_ELU) v = v > 0.f ? v : (__expf(v) - 1.f);
        Xout[(size_t)wid * HC + lane] = v;
    }
}

// ---------------------------------------------------------------------------
extern "C" void kernel_launch(void* const* d_in, const int* in_sizes, int n_in,
                              void* d_out, int out_size, void* d_ws, size_t ws_size,
                              hipStream_t stream) {
    const float* x     = (const float*)d_in[0];
    const int*   edges = (const int*)d_in[1];
    // d_in[2] = batch (unused)
    const float* W0 = (const float*)d_in[3];
    const float* as0 = (const float*)d_in[4];
    const float* ad0 = (const float*)d_in[5];
    const float* b0 = (const float*)d_in[6];
    const float* W1 = (const float*)d_in[7];
    const float* as1 = (const float*)d_in[8];
    const float* ad1 = (const float*)d_in[9];
    const float* b1 = (const float*)d_in[10];
    const float* W2 = (const float*)d_in[11];
    const float* as2 = (const float*)d_in[12];
    const float* ad2 = (const float*)d_in[13];
    const float* b2 = (const float*)d_in[14];

    const int n = in_sizes[0] / 64;
    const int E = in_sizes[1] / 2;
    const int EP = E + n;

    char* p = (char*)d_ws;
    auto alloc = [&](size_t bytes) {
        void* q = (void*)p;
        p += (bytes + 255) & ~(size_t)255;
        return q;
    };
    int*   deg     = (int*)alloc((size_t)n * 4);
    int*   row_ptr = (int*)alloc((size_t)(n + 1) * 4);
    int*   cursor  = (int*)alloc((size_t)n * 4);
    int*   ssrc    = (int*)alloc((size_t)EP * 4);
    float* hbuf    = (float*)alloc((size_t)n * 64 * 4);
    float* a_s     = (float*)alloc((size_t)n * 8 * 4);
    float* a_d     = (float*)alloc((size_t)n * 8 * 4);
    float* feat    = (float*)alloc((size_t)n * 64 * 4);
    (void)ws_size;

    hipMemsetAsync(deg, 0, (size_t)n * 4, stream);
    count_deg<<<(EP + 255) / 256, 256, 0, stream>>>(edges, E, n, deg);
    scan_rowptr<<<1, 1024, 0, stream>>>(deg, row_ptr, cursor, n);
    scatter_edges<<<(EP + 255) / 256, 256, 0, stream>>>(edges, E, n, cursor, ssrc);

    int gb = (n + 63) / 64;       // gemm blocks
    int ab = (n + 3) / 4;         // aggregate blocks (4 waves/block)

    // Layer 0: 64 -> 8x8, concat, ELU
    gemm64<64><<<gb, 256, 0, stream>>>(x, W0, hbuf, n);
    att_logits<8, 8><<<(n * 8 + 255) / 256, 256, 0, stream>>>(hbuf, as0, ad0, a_s, a_d, n);
    aggregate<8, 8, true><<<ab, 256, 0, stream>>>(row_ptr, ssrc, hbuf, a_s, a_d, b0, feat, n);

    // Layer 1: 64 -> 8x8, concat, ELU
    gemm64<64><<<gb, 256, 0, stream>>>(feat, W1, hbuf, n);
    att_logits<8, 8><<<(n * 8 + 255) / 256, 256, 0, stream>>>(hbuf, as1, ad1, a_s, a_d, n);
    aggregate<8, 8, true><<<ab, 256, 0, stream>>>(row_ptr, ssrc, hbuf, a_s, a_d, b1, feat, n);

    // Layer 2: 64 -> 1x32, mean(=identity), no ELU
    gemm64<32><<<gb, 256, 0, stream>>>(feat, W2, hbuf, n);
    att_logits<1, 32><<<(n + 255) / 256, 256, 0, stream>>>(hbuf, as2, ad2, a_s, a_d, n);
    aggregate<1, 32, false><<<ab, 256, 0, stream>>>(row_ptr, ssrc, hbuf, a_s, a_d, b2,
                                                    (float*)d_out, n);
}

// Round 2
// 616.297 us; speedup vs baseline: 1.9769x; 1.9769x over previous
//
#include <hip/hip_runtime.h>
#include <hip/hip_bf16.h>

// ---------------------------------------------------------------------------
// 3-layer GAT (PyG GATConv style) on MI355X.
// CSR build (histogram -> chunk-scan -> scatter), then per layer:
// GEMM (h = x@W), per-node logits, wave-per-node edge-softmax+aggregate with
// edge-parallel pass 1 (logits cached in LDS) and MLP-unrolled pass 2.
// ---------------------------------------------------------------------------

__device__ __forceinline__ float lrelu(float x) { return x > 0.f ? x : 0.2f * x; }

// ---- CSR build ------------------------------------------------------------
__global__ void count_deg(const int* __restrict__ edges, int E, int n,
                          int* __restrict__ deg) {
    int e = blockIdx.x * blockDim.x + threadIdx.x;
    int EP = E + n;
    if (e >= EP) return;
    int d = (e < E) ? edges[E + e] : (e - E);   // self-loop appended
    atomicAdd(&deg[d], 1);
}

__global__ __launch_bounds__(1024) void scan_rowptr(const int* __restrict__ deg,
                                                    int* __restrict__ row_ptr,
                                                    int* __restrict__ cursor, int n) {
    __shared__ int totals[1024];
    int tid = threadIdx.x;
    int per = (n + 1023) >> 10;
    int lo = tid * per, hi = min(n, lo + per);
    int sum = 0;
    for (int i = lo; i < hi; i++) sum += deg[i];
    totals[tid] = sum;
    __syncthreads();
    for (int off = 1; off < 1024; off <<= 1) {
        int t = (tid >= off) ? totals[tid - off] : 0;
        __syncthreads();
        totals[tid] += t;
        __syncthreads();
    }
    int run = totals[tid] - sum;                 // exclusive chunk offset
    for (int i = lo; i < hi; i++) {
        row_ptr[i] = run; cursor[i] = run; run += deg[i];
    }
    if (tid == 1023) row_ptr[n] = totals[1023];
}

__global__ void scatter_edges(const int* __restrict__ edges, int E, int n,
                              int* __restrict__ cursor, int* __restrict__ ssrc) {
    int e = blockIdx.x * blockDim.x + threadIdx.x;
    int EP = E + n;
    if (e >= EP) return;
    int s, d;
    if (e < E) { s = edges[e]; d = edges[E + e]; }
    else       { s = e - E;    d = e - E; }
    int p = atomicAdd(&cursor[d], 1);
    ssrc[p] = s;
}

// ---- h = X @ W  (X: n x 64, W: 64 x OUT) ----------------------------------
template <int OUT>
__global__ __launch_bounds__(256) void gemm64(const float* __restrict__ X,
                                              const float* __restrict__ W,
                                              float* __restrict__ Hout, int n) {
    __shared__ float xs[64][64];
    __shared__ float ws[64][OUT];
    int tid = threadIdx.x;
    int row0 = blockIdx.x * 64;
    for (int i = tid; i < 64 * OUT / 4; i += 256)
        ((float4*)&ws[0][0])[i] = ((const float4*)W)[i];
    for (int i = tid; i < 64 * 64 / 4; i += 256) {
        int r = (i * 4) / 64, c = (i * 4) % 64;
        int gr = row0 + r;
        float4 v = make_float4(0.f, 0.f, 0.f, 0.f);
        if (gr < n) v = ((const float4*)(X + (size_t)gr * 64))[c / 4];
        ((float4*)&xs[0][0])[i] = v;
    }
    __syncthreads();
    const int c = tid % OUT;
    const int RSTEP = 256 / OUT;
    for (int r = tid / OUT; r < 64; r += RSTEP) {
        int gr = row0 + r;
        if (gr >= n) break;
        float acc = 0.f;
#pragma unroll
        for (int k = 0; k < 64; k++) acc += xs[r][k] * ws[k][c];
        Hout[(size_t)gr * OUT + c] = acc;
    }
}

// ---- per-node attention logits -------------------------------------------
template <int H, int C>
__global__ void att_logits(const float* __restrict__ Hf, const float* __restrict__ att_s,
                           const float* __restrict__ att_d, float* __restrict__ a_src,
                           float* __restrict__ a_dst, int n) {
    int idx = blockIdx.x * blockDim.x + threadIdx.x;
    if (idx >= n * H) return;
    int node = idx / H, h = idx % H;
    const float* hp = Hf + (size_t)node * H * C + h * C;
    float ss = 0.f, sd = 0.f;
#pragma unroll
    for (int c = 0; c < C; c++) {
        float v = hp[c];
        ss += v * att_s[h * C + c];
        sd += v * att_d[h * C + c];
    }
    a_src[idx] = ss;
    a_dst[idx] = sd;
}

// ---- wave-per-node softmax + aggregate (+bias, +optional ELU) -------------
// Pass 1: 64/H lane-groups do 64/H edges/iter; raw logits cached in LDS.
// Pass 2: 64/(H*C) edges/iter, x4 unrolled for gather MLP.
template <int H, int C, bool DO_ELU>
__global__ __launch_bounds__(256) void aggregate(
    const int* __restrict__ row_ptr, const int* __restrict__ ssrc,
    const float* __restrict__ Hf, const float* __restrict__ a_src,
    const float* __restrict__ a_dst, const float* __restrict__ bias,
    float* __restrict__ Xout, int n) {
    constexpr int HC = H * C;
    constexpr int CAP = 128;                 // max cached edges per node
    constexpr int SLOTS = 64 / H;            // edges per iter, pass 1
    constexpr int EPI = 64 / HC;             // edges per iter, pass 2
    __shared__ float evbuf[4][CAP * H];

    int wid = (blockIdx.x * blockDim.x + threadIdx.x) >> 6;
    int lane = threadIdx.x & 63;
    int wv = threadIdx.x >> 6;
    bool live = wid < n;

    int start = 0, nloc = 0;
    if (live) { start = row_ptr[wid]; nloc = row_ptr[wid + 1] - start; }

    // ---- pass 1: online max+sum, edge-parallel across lane groups ----
    int hd = lane % H;
    int eg = lane / H;
    float m = -1e30f, ssum = 0.f;
    if (live) {
        float adst1 = a_dst[(size_t)wid * H + hd];
#pragma unroll 2
        for (int i = eg; i < nloc; i += SLOTS) {
            int s = ssrc[start + i];
            float ev = lrelu(a_src[(size_t)s * H + hd] + adst1);
            if (i < CAP) evbuf[wv][i * H + hd] = ev;
            if (ev <= m) ssum += __expf(ev - m);
            else { ssum = ssum * __expf(m - ev) + 1.f; m = ev; }
        }
    }
    // merge (m,ssum) across the SLOTS lane-groups sharing a head
#pragma unroll
    for (int mask = H; mask < 64; mask <<= 1) {
        float mo = __shfl_xor(m, mask);
        float so = __shfl_xor(ssum, mask);
        float mn = fmaxf(m, mo);
        ssum = ssum * __expf(m - mn) + so * __expf(mo - mn);
        m = mn;
    }
    float inv = 1.f / (ssum + 1e-16f);
    __syncthreads();                          // evbuf visible across lanes

    // ---- pass 2: weighted feature aggregation ----
    int ch = lane % HC;
    int sub = lane / HC;
    int head = ch / C;
    float m2 = __shfl(m, head);               // lane 'head' holds that head's m
    float inv2 = __shfl(inv, head);
    float acc = 0.f;
    if (live) {
        float adst2 = a_dst[(size_t)wid * H + head];
        auto alpha_at = [&](int i, int s) -> float {
            float ev = (i < CAP) ? evbuf[wv][i * H + head]
                                 : lrelu(a_src[(size_t)s * H + head] + adst2);
            return __expf(ev - m2) * inv2;
        };
        int i = sub;
        for (; i + 3 * EPI < nloc; i += 4 * EPI) {
            int i0 = i, i1 = i + EPI, i2 = i + 2 * EPI, i3 = i + 3 * EPI;
            int s0 = ssrc[start + i0], s1 = ssrc[start + i1];
            int s2 = ssrc[start + i2], s3 = ssrc[start + i3];
            float f0 = Hf[(size_t)s0 * HC + ch];
            float f1 = Hf[(size_t)s1 * HC + ch];
            float f2 = Hf[(size_t)s2 * HC + ch];
            float f3 = Hf[(size_t)s3 * HC + ch];
            acc += alpha_at(i0, s0) * f0 + alpha_at(i1, s1) * f1 +
                   alpha_at(i2, s2) * f2 + alpha_at(i3, s3) * f3;
        }
        for (; i < nloc; i += EPI) {
            int s = ssrc[start + i];
            acc += alpha_at(i, s) * Hf[(size_t)s * HC + ch];
        }
    }
    // combine partial accs across edge-sublanes (no-op when EPI==1)
#pragma unroll
    for (int mask = HC; mask < 64; mask <<= 1) acc += __shfl_xor(acc, mask);

    if (live && lane < HC) {
        float v = acc + bias[lane];
        if (DO_ELU) v = v > 0.f ? v : (__expf(v) - 1.f);
        Xout[(size_t)wid * HC + lane] = v;
    }
}

// ---------------------------------------------------------------------------
extern "C" void kernel_launch(void* const* d_in, const int* in_sizes, int n_in,
                              void* d_out, int out_size, void* d_ws, size_t ws_size,
                              hipStream_t stream) {
    const float* x     = (const float*)d_in[0];
    const int*   edges = (const int*)d_in[1];
    // d_in[2] = batch (unused)
    const float* W0 = (const float*)d_in[3];
    const float* as0 = (const float*)d_in[4];
    const float* ad0 = (const float*)d_in[5];
    const float* b0 = (const float*)d_in[6];
    const float* W1 = (const float*)d_in[7];
    const float* as1 = (const float*)d_in[8];
    const float* ad1 = (const float*)d_in[9];
    const float* b1 = (const float*)d_in[10];
    const float* W2 = (const float*)d_in[11];
    const float* as2 = (const float*)d_in[12];
    const float* ad2 = (const float*)d_in[13];
    const float* b2 = (const float*)d_in[14];

    const int n = in_sizes[0] / 64;
    const int E = in_sizes[1] / 2;
    const int EP = E + n;

    char* p = (char*)d_ws;
    auto alloc = [&](size_t bytes) {
        void* q = (void*)p;
        p += (bytes + 255) & ~(size_t)255;
        return q;
    };
    int*   deg     = (int*)alloc((size_t)n * 4);
    int*   row_ptr = (int*)alloc((size_t)(n + 1) * 4);
    int*   cursor  = (int*)alloc((size_t)n * 4);
    int*   ssrc    = (int*)alloc((size_t)EP * 4);
    float* hbuf    = (float*)alloc((size_t)n * 64 * 4);
    float* a_s     = (float*)alloc((size_t)n * 8 * 4);
    float* a_d     = (float*)alloc((size_t)n * 8 * 4);
    float* feat    = (float*)alloc((size_t)n * 64 * 4);
    (void)ws_size;

    hipMemsetAsync(deg, 0, (size_t)n * 4, stream);
    count_deg<<<(EP + 255) / 256, 256, 0, stream>>>(edges, E, n, deg);
    scan_rowptr<<<1, 1024, 0, stream>>>(deg, row_ptr, cursor, n);
    scatter_edges<<<(EP + 255) / 256, 256, 0, stream>>>(edges, E, n, cursor, ssrc);

    int gb = (n + 63) / 64;       // gemm blocks
    int ab = (n + 3) / 4;         // aggregate blocks (4 waves/block)

    // Layer 0: 64 -> 8x8, concat, ELU
    gemm64<64><<<gb, 256, 0, stream>>>(x, W0, hbuf, n);
    att_logits<8, 8><<<(n * 8 + 255) / 256, 256, 0, stream>>>(hbuf, as0, ad0, a_s, a_d, n);
    aggregate<8, 8, true><<<ab, 256, 0, stream>>>(row_ptr, ssrc, hbuf, a_s, a_d, b0, feat, n);

    // Layer 1: 64 -> 8x8, concat, ELU
    gemm64<64><<<gb, 256, 0, stream>>>(feat, W1, hbuf, n);
    att_logits<8, 8><<<(n * 8 + 255) / 256, 256, 0, stream>>>(hbuf, as1, ad1, a_s, a_d, n);
    aggregate<8, 8, true><<<ab, 256, 0, stream>>>(row_ptr, ssrc, hbuf, a_s, a_d, b1, feat, n);

    // Layer 2: 64 -> 1x32, mean(=identity), no ELU
    gemm64<32><<<gb, 256, 0, stream>>>(feat, W2, hbuf, n);
    att_logits<1, 32><<<(n + 255) / 256, 256, 0, stream>>>(hbuf, as2, ad2, a_s, a_d, n);
    aggregate<1, 32, false><<<ab, 256, 0, stream>>>(row_ptr, ssrc, hbuf, a_s, a_d, b2,
                                                    (float*)d_out, n);
}

// Round 4
// 381.775 us; speedup vs baseline: 3.1914x; 1.6143x over previous
//
#include <hip/hip_runtime.h>
#include <hip/hip_bf16.h>

// ---------------------------------------------------------------------------
// 3-layer GAT (PyG GATConv style) on MI355X.
// CSR build via two-level bucketed counting sort (bucket = dst>>6, so bucket
// regions are contiguous CSR regions; all random writes stay L2-resident).
// Then per layer: GEMM (h = x@W), per-node logits, wave-per-node
// edge-softmax+aggregate (edge-parallel pass 1 w/ LDS logit cache, unrolled
// gather pass 2). All fp32. Assumes n <= 65536 (src packed in 16 bits).
// ---------------------------------------------------------------------------

__device__ __forceinline__ float lrelu(float x) { return x > 0.f ? x : 0.2f * x; }

#define PCHUNK 8192

// ---- CSR build ------------------------------------------------------------
__global__ __launch_bounds__(256) void bucket_count(const int* __restrict__ edges,
                                                    int E, int n, int NB,
                                                    int* __restrict__ bdeg) {
    __shared__ int hist[1024];
    for (int i = threadIdx.x; i < NB; i += 256) hist[i] = 0;
    __syncthreads();
    int EP = E + n;
    int stride = gridDim.x * blockDim.x;
    for (int e = blockIdx.x * blockDim.x + threadIdx.x; e < EP; e += stride) {
        int d = (e < E) ? edges[E + e] : (e - E);   // self-loop appended
        atomicAdd(&hist[d >> 6], 1);
    }
    __syncthreads();
    for (int i = threadIdx.x; i < NB; i += 256)
        if (hist[i]) atomicAdd(&bdeg[i], hist[i]);
}

__global__ __launch_bounds__(1024) void bucket_scan(const int* __restrict__ bdeg,
                                                    int* __restrict__ bstart,
                                                    int* __restrict__ bcursor,
                                                    int* __restrict__ row_ptr,
                                                    int NB, int n, int EP) {
    __shared__ int buf[1024];
    int tid = threadIdx.x;
    int v = (tid < NB) ? bdeg[tid] : 0;
    buf[tid] = v;
    __syncthreads();
    for (int off = 1; off < 1024; off <<= 1) {
        int t = (tid >= off) ? buf[tid - off] : 0;
        __syncthreads();
        buf[tid] += t;
        __syncthreads();
    }
    if (tid < NB) { bstart[tid] = buf[tid] - v; bcursor[tid] = buf[tid] - v; }
    if (tid == 0) { bstart[NB] = EP; row_ptr[n] = EP; }
}

// Partition edges into bucket-major order (unsorted within bucket), packed as
// src | (dst&63)<<16. Per-block LDS histogram + one global reserve per bucket.
__global__ __launch_bounds__(256) void partition(const int* __restrict__ edges,
                                                 int E, int n, int NB,
                                                 int* __restrict__ bcursor,
                                                 unsigned* __restrict__ T) {
    __shared__ int hist[1024];
    __shared__ int base[1024];
    int EP = E + n;
    int e0 = blockIdx.x * PCHUNK;
    int e1 = min(EP, e0 + PCHUNK);
    for (int i = threadIdx.x; i < NB; i += 256) hist[i] = 0;
    __syncthreads();
    for (int e = e0 + threadIdx.x; e < e1; e += 256) {
        int d = (e < E) ? edges[E + e] : (e - E);
        atomicAdd(&hist[d >> 6], 1);
    }
    __syncthreads();
    for (int i = threadIdx.x; i < NB; i += 256) {
        int c = hist[i];
        base[i] = c ? atomicAdd(&bcursor[i], c) : 0;
        hist[i] = 0;          // same thread owns this index in both loops
    }
    __syncthreads();
    for (int e = e0 + threadIdx.x; e < e1; e += 256) {
        int s, d;
        if (e < E) { s = edges[e]; d = edges[E + e]; }
        else       { s = e - E;    d = e - E; }
        int b = d >> 6;
        int r = atomicAdd(&hist[b], 1);
        T[base[b] + r] = (unsigned)s | ((unsigned)(d & 63) << 16);
    }
}

// Per-bucket counting sort by dst low bits; emits row_ptr and sorted ssrc.
__global__ __launch_bounds__(256) void bucket_sort(const unsigned* __restrict__ T,
                                                   const int* __restrict__ bstart,
                                                   int n, int* __restrict__ row_ptr,
                                                   int* __restrict__ ssrc) {
    __shared__ int cnt[64];
    int b = blockIdx.x;
    int s0 = bstart[b], s1 = bstart[b + 1];
    int node0 = b << 6;
    if (threadIdx.x < 64) cnt[threadIdx.x] = 0;
    __syncthreads();
    for (int i = s0 + threadIdx.x; i < s1; i += 256)
        atomicAdd(&cnt[(T[i] >> 16) & 63], 1);
    __syncthreads();
    if (threadIdx.x < 64) {
        int v = cnt[threadIdx.x];
        int p = v;
        for (int o = 1; o < 64; o <<= 1) {
            int t = __shfl_up(p, o);
            if ((int)threadIdx.x >= o) p += t;
        }
        int excl = p - v;
        if (node0 + (int)threadIdx.x < n) row_ptr[node0 + threadIdx.x] = s0 + excl;
        cnt[threadIdx.x] = excl;          // reuse as running cursor
    }
    __syncthreads();
    for (int i = s0 + threadIdx.x; i < s1; i += 256) {
        unsigned t = T[i];
        int r = atomicAdd(&cnt[(t >> 16) & 63], 1);
        ssrc[s0 + r] = (int)(t & 0xFFFFu);
    }
}

// ---- h = X @ W  (X: n x 64, W: 64 x OUT) ----------------------------------
template <int OUT>
__global__ __launch_bounds__(256) void gemm64(const float* __restrict__ X,
                                              const float* __restrict__ W,
                                              float* __restrict__ Hout, int n) {
    __shared__ float xs[64][64];
    __shared__ float ws[64][OUT];
    int tid = threadIdx.x;
    int row0 = blockIdx.x * 64;
    for (int i = tid; i < 64 * OUT / 4; i += 256)
        ((float4*)&ws[0][0])[i] = ((const float4*)W)[i];
    for (int i = tid; i < 64 * 64 / 4; i += 256) {
        int r = (i * 4) / 64, c = (i * 4) % 64;
        int gr = row0 + r;
        float4 v = make_float4(0.f, 0.f, 0.f, 0.f);
        if (gr < n) v = ((const float4*)(X + (size_t)gr * 64))[c / 4];
        ((float4*)&xs[0][0])[i] = v;
    }
    __syncthreads();
    const int c = tid % OUT;
    const int RSTEP = 256 / OUT;
    for (int r = tid / OUT; r < 64; r += RSTEP) {
        int gr = row0 + r;
        if (gr >= n) break;
        float acc = 0.f;
#pragma unroll
        for (int k = 0; k < 64; k++) acc += xs[r][k] * ws[k][c];
        Hout[(size_t)gr * OUT + c] = acc;
    }
}

// ---- per-node attention logits -------------------------------------------
template <int H, int C>
__global__ void att_logits(const float* __restrict__ Hf, const float* __restrict__ att_s,
                           const float* __restrict__ att_d, float* __restrict__ a_src,
                           float* __restrict__ a_dst, int n) {
    int idx = blockIdx.x * blockDim.x + threadIdx.x;
    if (idx >= n * H) return;
    int node = idx / H, h = idx % H;
    const float* hp = Hf + (size_t)node * H * C + h * C;
    float ss = 0.f, sd = 0.f;
#pragma unroll
    for (int c = 0; c < C; c++) {
        float v = hp[c];
        ss += v * att_s[h * C + c];
        sd += v * att_d[h * C + c];
    }
    a_src[idx] = ss;
    a_dst[idx] = sd;
}

// ---- wave-per-node softmax + aggregate (+bias, +optional ELU) -------------
template <int H, int C, bool DO_ELU>
__global__ __launch_bounds__(256) void aggregate(
    const int* __restrict__ row_ptr, const int* __restrict__ ssrc,
    const float* __restrict__ Hf, const float* __restrict__ a_src,
    const float* __restrict__ a_dst, const float* __restrict__ bias,
    float* __restrict__ Xout, int n) {
    constexpr int HC = H * C;
    constexpr int CAP = 128;                 // max cached edges per node
    constexpr int SLOTS = 64 / H;            // edges per iter, pass 1
    constexpr int EPI = 64 / HC;             // edges per iter, pass 2
    __shared__ float evbuf[4][CAP * H];

    int wid = (blockIdx.x * blockDim.x + threadIdx.x) >> 6;
    int lane = threadIdx.x & 63;
    int wv = threadIdx.x >> 6;
    bool live = wid < n;

    int start = 0, nloc = 0;
    if (live) { start = row_ptr[wid]; nloc = row_ptr[wid + 1] - start; }

    // ---- pass 1: online max+sum, edge-parallel across lane groups ----
    int hd = lane % H;
    int eg = lane / H;
    float m = -1e30f, ssum = 0.f;
    if (live) {
        float adst1 = a_dst[(size_t)wid * H + hd];
#pragma unroll 2
        for (int i = eg; i < nloc; i += SLOTS) {
            int s = ssrc[start + i];
            float ev = lrelu(a_src[(size_t)s * H + hd] + adst1);
            if (i < CAP) evbuf[wv][i * H + hd] = ev;
            if (ev <= m) ssum += __expf(ev - m);
            else { ssum = ssum * __expf(m - ev) + 1.f; m = ev; }
        }
    }
#pragma unroll
    for (int mask = H; mask < 64; mask <<= 1) {
        float mo = __shfl_xor(m, mask);
        float so = __shfl_xor(ssum, mask);
        float mn = fmaxf(m, mo);
        ssum = ssum * __expf(m - mn) + so * __expf(mo - mn);
        m = mn;
    }
    float inv = 1.f / (ssum + 1e-16f);
    __syncthreads();                          // evbuf visible across lanes

    // ---- pass 2: weighted feature aggregation ----
    int ch = lane % HC;
    int sub = lane / HC;
    int head = ch / C;
    float m2 = __shfl(m, head);
    float inv2 = __shfl(inv, head);
    float acc = 0.f;
    if (live) {
        float adst2 = a_dst[(size_t)wid * H + head];
        auto alpha_at = [&](int i, int s) -> float {
            float ev = (i < CAP) ? evbuf[wv][i * H + head]
                                 : lrelu(a_src[(size_t)s * H + head] + adst2);
            return __expf(ev - m2) * inv2;
        };
        int i = sub;
        for (; i + 3 * EPI < nloc; i += 4 * EPI) {
            int i0 = i, i1 = i + EPI, i2 = i + 2 * EPI, i3 = i + 3 * EPI;
            int s0 = ssrc[start + i0], s1 = ssrc[start + i1];
            int s2 = ssrc[start + i2], s3 = ssrc[start + i3];
            float f0 = Hf[(size_t)s0 * HC + ch];
            float f1 = Hf[(size_t)s1 * HC + ch];
            float f2 = Hf[(size_t)s2 * HC + ch];
            float f3 = Hf[(size_t)s3 * HC + ch];
            acc += alpha_at(i0, s0) * f0 + alpha_at(i1, s1) * f1 +
                   alpha_at(i2, s2) * f2 + alpha_at(i3, s3) * f3;
        }
        for (; i < nloc; i += EPI) {
            int s = ssrc[start + i];
            acc += alpha_at(i, s) * Hf[(size_t)s * HC + ch];
        }
    }
#pragma unroll
    for (int mask = HC; mask < 64; mask <<= 1) acc += __shfl_xor(acc, mask);

    if (live && lane < HC) {
        float v = acc + bias[lane];
        if (DO_ELU) v = v > 0.f ? v : (__expf(v) - 1.f);
        Xout[(size_t)wid * HC + lane] = v;
    }
}

// ---------------------------------------------------------------------------
extern "C" void kernel_launch(void* const* d_in, const int* in_sizes, int n_in,
                              void* d_out, int out_size, void* d_ws, size_t ws_size,
                              hipStream_t stream) {
    const float* x     = (const float*)d_in[0];
    const int*   edges = (const int*)d_in[1];
    // d_in[2] = batch (unused)
    const float* W0 = (const float*)d_in[3];
    const float* as0 = (const float*)d_in[4];
    const float* ad0 = (const float*)d_in[5];
    const float* b0 = (const float*)d_in[6];
    const float* W1 = (const float*)d_in[7];
    const float* as1 = (const float*)d_in[8];
    const float* ad1 = (const float*)d_in[9];
    const float* b1 = (const float*)d_in[10];
    const float* W2 = (const float*)d_in[11];
    const float* as2 = (const float*)d_in[12];
    const float* ad2 = (const float*)d_in[13];
    const float* b2 = (const float*)d_in[14];

    const int n = in_sizes[0] / 64;
    const int E = in_sizes[1] / 2;
    const int EP = E + n;
    const int NB = (n + 63) >> 6;              // buckets (<=1024 for n<=65536)

    char* p = (char*)d_ws;
    auto alloc = [&](size_t bytes) {
        void* q = (void*)p;
        p += (bytes + 255) & ~(size_t)255;
        return q;
    };
    int*   bdeg    = (int*)alloc((size_t)NB * 4);
    int*   bstart  = (int*)alloc((size_t)(NB + 1) * 4);
    int*   bcursor = (int*)alloc((size_t)NB * 4);
    int*   row_ptr = (int*)alloc((size_t)(n + 1) * 4);
    int*   ssrc    = (int*)alloc((size_t)EP * 4);
    float* hbuf    = (float*)alloc((size_t)n * 64 * 4);
    float* a_s     = (float*)alloc((size_t)n * 8 * 4);
    float* a_d     = (float*)alloc((size_t)n * 8 * 4);
    float* feat    = (float*)alloc((size_t)n * 64 * 4);
    (void)ws_size;
    // T aliases hbuf: consumed by bucket_sort before the first GEMM writes hbuf.
    unsigned* T = (unsigned*)hbuf;

    hipMemsetAsync(bdeg, 0, (size_t)NB * 4, stream);
    bucket_count<<<256, 256, 0, stream>>>(edges, E, n, NB, bdeg);
    bucket_scan<<<1, 1024, 0, stream>>>(bdeg, bstart, bcursor, row_ptr, NB, n, EP);
    partition<<<(EP + PCHUNK - 1) / PCHUNK, 256, 0, stream>>>(edges, E, n, NB, bcursor, T);
    bucket_sort<<<NB, 256, 0, stream>>>(T, bstart, n, row_ptr, ssrc);

    int gb = (n + 63) / 64;       // gemm blocks
    int ab = (n + 3) / 4;         // aggregate blocks (4 waves/block)

    // Layer 0: 64 -> 8x8, concat, ELU
    gemm64<64><<<gb, 256, 0, stream>>>(x, W0, hbuf, n);
    att_logits<8, 8><<<(n * 8 + 255) / 256, 256, 0, stream>>>(hbuf, as0, ad0, a_s, a_d, n);
    aggregate<8, 8, true><<<ab, 256, 0, stream>>>(row_ptr, ssrc, hbuf, a_s, a_d, b0, feat, n);

    // Layer 1: 64 -> 8x8, concat, ELU
    gemm64<64><<<gb, 256, 0, stream>>>(feat, W1, hbuf, n);
    att_logits<8, 8><<<(n * 8 + 255) / 256, 256, 0, stream>>>(hbuf, as1, ad1, a_s, a_d, n);
    aggregate<8, 8, true><<<ab, 256, 0, stream>>>(row_ptr, ssrc, hbuf, a_s, a_d, b1, feat, n);

    // Layer 2: 64 -> 1x32, mean(=identity), no ELU
    gemm64<32><<<gb, 256, 0, stream>>>(feat, W2, hbuf, n);
    att_logits<1, 32><<<(n + 255) / 256, 256, 0, stream>>>(hbuf, as2, ad2, a_s, a_d, n);
    aggregate<1, 32, false><<<ab, 256, 0, stream>>>(row_ptr, ssrc, hbuf, a_s, a_d, b2,
                                                    (float*)d_out, n);
}

// Round 9
// 328.783 us; speedup vs baseline: 3.7057x; 1.1612x over previous
//
#include <hip/hip_runtime.h>
#include <hip/hip_bf16.h>

// ---------------------------------------------------------------------------
// 3-layer GAT (PyG GATConv style) on MI355X.
// CSR build via two-level bucketed counting sort (bucket = dst>>6).
// Per layer: fused GEMM+attention-logits, then wave-per-node edge-softmax +
// aggregate: pass 1 = fmax sweep (LDS logit cache) + LDS exp sweep;
// pass 2 = float4-lane gather, 4 (or 8) edges per wave-iteration.
// All fp32. Assumes n <= 65536 (src packed in 16 bits in the sort).
// ---------------------------------------------------------------------------

__device__ __forceinline__ float lrelu(float x) { return x > 0.f ? x : 0.2f * x; }

#define PCHUNK 8192

// ---- CSR build ------------------------------------------------------------
__global__ __launch_bounds__(256) void bucket_count(const int* __restrict__ edges,
                                                    int E, int n, int NB,
                                                    int* __restrict__ bdeg) {
    __shared__ int hist[1024];
    for (int i = threadIdx.x; i < NB; i += 256) hist[i] = 0;
    __syncthreads();
    int EP = E + n;
    int stride = gridDim.x * blockDim.x;
    for (int e = blockIdx.x * blockDim.x + threadIdx.x; e < EP; e += stride) {
        int d = (e < E) ? edges[E + e] : (e - E);   // self-loop appended
        atomicAdd(&hist[d >> 6], 1);
    }
    __syncthreads();
    for (int i = threadIdx.x; i < NB; i += 256)
        if (hist[i]) atomicAdd(&bdeg[i], hist[i]);
}

__global__ __launch_bounds__(1024) void bucket_scan(const int* __restrict__ bdeg,
                                                    int* __restrict__ bstart,
                                                    int* __restrict__ bcursor,
                                                    int* __restrict__ row_ptr,
                                                    int NB, int n, int EP) {
    __shared__ int buf[1024];
    int tid = threadIdx.x;
    int v = (tid < NB) ? bdeg[tid] : 0;
    buf[tid] = v;
    __syncthreads();
    for (int off = 1; off < 1024; off <<= 1) {
        int t = (tid >= off) ? buf[tid - off] : 0;
        __syncthreads();
        buf[tid] += t;
        __syncthreads();
    }
    if (tid < NB) { bstart[tid] = buf[tid] - v; bcursor[tid] = buf[tid] - v; }
    if (tid == 0) { bstart[NB] = EP; row_ptr[n] = EP; }
}

__global__ __launch_bounds__(256) void partition(const int* __restrict__ edges,
                                                 int E, int n, int NB,
                                                 int* __restrict__ bcursor,
                                                 unsigned* __restrict__ T) {
    __shared__ int hist[1024];
    __shared__ int base[1024];
    int EP = E + n;
    int e0 = blockIdx.x * PCHUNK;
    int e1 = min(EP, e0 + PCHUNK);
    for (int i = threadIdx.x; i < NB; i += 256) hist[i] = 0;
    __syncthreads();
    for (int e = e0 + threadIdx.x; e < e1; e += 256) {
        int d = (e < E) ? edges[E + e] : (e - E);
        atomicAdd(&hist[d >> 6], 1);
    }
    __syncthreads();
    for (int i = threadIdx.x; i < NB; i += 256) {
        int c = hist[i];
        base[i] = c ? atomicAdd(&bcursor[i], c) : 0;
        hist[i] = 0;          // same thread owns this index in both loops
    }
    __syncthreads();
    for (int e = e0 + threadIdx.x; e < e1; e += 256) {
        int s, d;
        if (e < E) { s = edges[e]; d = edges[E + e]; }
        else       { s = e - E;    d = e - E; }
        int b = d >> 6;
        int r = atomicAdd(&hist[b], 1);
        T[base[b] + r] = (unsigned)s | ((unsigned)(d & 63) << 16);
    }
}

__global__ __launch_bounds__(256) void bucket_sort(const unsigned* __restrict__ T,
                                                   const int* __restrict__ bstart,
                                                   int n, int* __restrict__ row_ptr,
                                                   int* __restrict__ ssrc) {
    __shared__ int cnt[64];
    int b = blockIdx.x;
    int s0 = bstart[b], s1 = bstart[b + 1];
    int node0 = b << 6;
    if (threadIdx.x < 64) cnt[threadIdx.x] = 0;
    __syncthreads();
    for (int i = s0 + threadIdx.x; i < s1; i += 256)
        atomicAdd(&cnt[(T[i] >> 16) & 63], 1);
    __syncthreads();
    if (threadIdx.x < 64) {
        int v = cnt[threadIdx.x];
        int p = v;
        for (int o = 1; o < 64; o <<= 1) {
            int t = __shfl_up(p, o);
            if ((int)threadIdx.x >= o) p += t;
        }
        int excl = p - v;
        if (node0 + (int)threadIdx.x < n) row_ptr[node0 + threadIdx.x] = s0 + excl;
        cnt[threadIdx.x] = excl;          // reuse as running cursor
    }
    __syncthreads();
    for (int i = s0 + threadIdx.x; i < s1; i += 256) {
        unsigned t = T[i];
        int r = atomicAdd(&cnt[(t >> 16) & 63], 1);
        ssrc[s0 + r] = (int)(t & 0xFFFFu);
    }
}

// ---- fused h = X @ W and per-node attention logits ------------------------
// Row r's OUT channels live in one contiguous lane segment -> segment shfl
// reduction produces a_src/a_dst without a separate kernel.
template <int OUT, int H>
__global__ __launch_bounds__(256) void gemm_att(const float* __restrict__ X,
                                                const float* __restrict__ W,
                                                const float* __restrict__ att_s,
                                                const float* __restrict__ att_d,
                                                float* __restrict__ Hout,
                                                float* __restrict__ a_src,
                                                float* __restrict__ a_dst, int n) {
    constexpr int C = OUT / H;
    __shared__ float xs[64][64];
    __shared__ float ws[64][OUT];
    int tid = threadIdx.x;
    int row0 = blockIdx.x * 64;
    for (int i = tid; i < 64 * OUT / 4; i += 256)
        ((float4*)&ws[0][0])[i] = ((const float4*)W)[i];
    for (int i = tid; i < 64 * 64 / 4; i += 256) {
        int r = (i * 4) / 64, c = (i * 4) % 64;
        int gr = row0 + r;
        float4 v = make_float4(0.f, 0.f, 0.f, 0.f);
        if (gr < n) v = ((const float4*)(X + (size_t)gr * 64))[c / 4];
        ((float4*)&xs[0][0])[i] = v;
    }
    __syncthreads();
    const int c = tid % OUT;
    const float asv = att_s[c], adv = att_d[c];   // (H,C) packed == [c]
    const int RSTEP = 256 / OUT;
    for (int r = tid / OUT; r < 64; r += RSTEP) {
        int gr = row0 + r;
        float acc = 0.f;
#pragma unroll
        for (int k = 0; k < 64; k++) acc += xs[r][k] * ws[k][c];
        float ts = acc * asv, td = acc * adv;
#pragma unroll
        for (int mask = 1; mask < C; mask <<= 1) {
            ts += __shfl_xor(ts, mask);
            td += __shfl_xor(td, mask);
        }
        if (gr < n) {
            Hout[(size_t)gr * OUT + c] = acc;
            if (c % C == 0) {
                a_src[(size_t)gr * H + c / C] = ts;
                a_dst[(size_t)gr * H + c / C] = td;
            }
        }
    }
}

// ---- wave-per-node softmax + aggregate (+bias, +optional ELU) -------------
template <int H, int C, bool DO_ELU>
__global__ __launch_bounds__(256) void aggregate(
    const int* __restrict__ row_ptr, const int* __restrict__ ssrc,
    const float* __restrict__ Hf, const float* __restrict__ a_src,
    const float* __restrict__ a_dst, const float* __restrict__ bias,
    float* __restrict__ Xout, int n) {
    constexpr int HC = H * C;
    constexpr int CAP = 128;                 // max cached edges per node
    constexpr int SLOTS = 64 / H;            // pass-1 edges per iteration
    constexpr int LPR = HC / 4;              // pass-2 lanes per row (float4)
    constexpr int EPG = 64 / LPR;            // pass-2 edges per iteration
    __shared__ float evbuf[4][CAP * H];

    int wid = (blockIdx.x * blockDim.x + threadIdx.x) >> 6;
    int lane = threadIdx.x & 63;
    int wv = threadIdx.x >> 6;
    bool live = wid < n;

    int start = 0, nloc = 0;
    if (live) { start = row_ptr[wid]; nloc = row_ptr[wid + 1] - start; }

    // ---- pass 1, sweep A: gather logits, cache in LDS, track max ----
    int hd = lane % H;
    int eg = lane / H;
    float m = -1e30f;
    float adst1 = live ? a_dst[(size_t)wid * H + hd] : 0.f;
    if (live) {
        for (int i = eg; i < nloc; i += SLOTS) {
            int s = ssrc[start + i];
            float ev = lrelu(a_src[(size_t)s * H + hd] + adst1);
            if (i < CAP) evbuf[wv][i * H + hd] = ev;
            m = fmaxf(m, ev);
        }
    }
#pragma unroll
    for (int mask = H; mask < 64; mask <<= 1) m = fmaxf(m, __shfl_xor(m, mask));

    // ---- pass 1, sweep B: sum of exp from the LDS cache ----
    float ssum = 0.f;
    if (live) {
        for (int i = eg; i < nloc; i += SLOTS) {
            float ev;
            if (i < CAP) ev = evbuf[wv][i * H + hd];
            else {
                int s = ssrc[start + i];
                ev = lrelu(a_src[(size_t)s * H + hd] + adst1);
            }
            ssum += __expf(ev - m);
        }
    }
#pragma unroll
    for (int mask = H; mask < 64; mask <<= 1) ssum += __shfl_xor(ssum, mask);
    float inv = 1.f / (ssum + 1e-16f);
    __syncthreads();                          // evbuf visible across lanes

    // ---- pass 2: float4-lane weighted gather, EPG edges per iteration ----
    int lr = lane % LPR;                      // lane-in-row
    int sub = lane / LPR;                     // edge slot in group
    int head2 = (lr * 4) / C;                 // head owning channels lr*4..+3
    float m2 = __shfl(m, head2);              // lane h holds head h's merged m
    float inv2 = __shfl(inv, head2);
    float4 acc = make_float4(0.f, 0.f, 0.f, 0.f);
    if (live) {
        float adst2 = a_dst[(size_t)wid * H + head2];
#pragma unroll 2
        for (int i = 0; i < nloc; i += EPG) {
            int ii = i + sub;
            float alpha = 0.f;
            int s = 0;
            if (ii < nloc) {
                s = ssrc[start + ii];
                float ev = (ii < CAP) ? evbuf[wv][ii * H + head2]
                                      : lrelu(a_src[(size_t)s * H + head2] + adst2);
                alpha = __expf(ev - m2) * inv2;
            }
            float4 f = ((const float4*)(Hf + (size_t)s * HC))[lr];
            acc.x += alpha * f.x; acc.y += alpha * f.y;
            acc.z += alpha * f.z; acc.w += alpha * f.w;
        }
    }
#pragma unroll
    for (int mask = LPR; mask < 64; mask <<= 1) {
        acc.x += __shfl_xor(acc.x, mask);
        acc.y += __shfl_xor(acc.y, mask);
        acc.z += __shfl_xor(acc.z, mask);
        acc.w += __shfl_xor(acc.w, mask);
    }
    if (live && lane < LPR) {
        float4 bv = ((const float4*)bias)[lr];
        float4 v;
        v.x = acc.x + bv.x; v.y = acc.y + bv.y;
        v.z = acc.z + bv.z; v.w = acc.w + bv.w;
        if (DO_ELU) {
            v.x = v.x > 0.f ? v.x : (__expf(v.x) - 1.f);
            v.y = v.y > 0.f ? v.y : (__expf(v.y) - 1.f);
            v.z = v.z > 0.f ? v.z : (__expf(v.z) - 1.f);
            v.w = v.w > 0.f ? v.w : (__expf(v.w) - 1.f);
        }
        ((float4*)(Xout + (size_t)wid * HC))[lr] = v;
    }
}

// ---------------------------------------------------------------------------
extern "C" void kernel_launch(void* const* d_in, const int* in_sizes, int n_in,
                              void* d_out, int out_size, void* d_ws, size_t ws_size,
                              hipStream_t stream) {
    const float* x     = (const float*)d_in[0];
    const int*   edges = (const int*)d_in[1];
    // d_in[2] = batch (unused)
    const float* W0 = (const float*)d_in[3];
    const float* as0 = (const float*)d_in[4];
    const float* ad0 = (const float*)d_in[5];
    const float* b0 = (const float*)d_in[6];
    const float* W1 = (const float*)d_in[7];
    const float* as1 = (const float*)d_in[8];
    const float* ad1 = (const float*)d_in[9];
    const float* b1 = (const float*)d_in[10];
    const float* W2 = (const float*)d_in[11];
    const float* as2 = (const float*)d_in[12];
    const float* ad2 = (const float*)d_in[13];
    const float* b2 = (const float*)d_in[14];

    const int n = in_sizes[0] / 64;
    const int E = in_sizes[1] / 2;
    const int EP = E + n;
    const int NB = (n + 63) >> 6;              // buckets (<=1024 for n<=65536)

    char* p = (char*)d_ws;
    auto alloc = [&](size_t bytes) {
        void* q = (void*)p;
        p += (bytes + 255) & ~(size_t)255;
        return q;
    };
    int*   bdeg    = (int*)alloc((size_t)NB * 4);
    int*   bstart  = (int*)alloc((size_t)(NB + 1) * 4);
    int*   bcursor = (int*)alloc((size_t)NB * 4);
    int*   row_ptr = (int*)alloc((size_t)(n + 1) * 4);
    int*   ssrc    = (int*)alloc((size_t)EP * 4);
    float* hbuf    = (float*)alloc((size_t)n * 64 * 4);
    float* a_s     = (float*)alloc((size_t)n * 8 * 4);
    float* a_d     = (float*)alloc((size_t)n * 8 * 4);
    float* feat    = (float*)alloc((size_t)n * 64 * 4);
    (void)ws_size;
    // T aliases hbuf: consumed by bucket_sort before the first GEMM writes hbuf.
    unsigned* T = (unsigned*)hbuf;

    hipMemsetAsync(bdeg, 0, (size_t)NB * 4, stream);
    bucket_count<<<256, 256, 0, stream>>>(edges, E, n, NB, bdeg);
    bucket_scan<<<1, 1024, 0, stream>>>(bdeg, bstart, bcursor, row_ptr, NB, n, EP);
    partition<<<(EP + PCHUNK - 1) / PCHUNK, 256, 0, stream>>>(edges, E, n, NB, bcursor, T);
    bucket_sort<<<NB, 256, 0, stream>>>(T, bstart, n, row_ptr, ssrc);

    int gb = (n + 63) / 64;       // gemm blocks
    int ab = (n + 3) / 4;         // aggregate blocks (4 waves/block)

    // Layer 0: 64 -> 8x8, concat, ELU
    gemm_att<64, 8><<<gb, 256, 0, stream>>>(x, W0, as0, ad0, hbuf, a_s, a_d, n);
    aggregate<8, 8, true><<<ab, 256, 0, stream>>>(row_ptr, ssrc, hbuf, a_s, a_d, b0, feat, n);

    // Layer 1: 64 -> 8x8, concat, ELU
    gemm_att<64, 8><<<gb, 256, 0, stream>>>(feat, W1, as1, ad1, hbuf, a_s, a_d, n);
    aggregate<8, 8, true><<<ab, 256, 0, stream>>>(row_ptr, ssrc, hbuf, a_s, a_d, b1, feat, n);

    // Layer 2: 64 -> 1x32, mean(=identity), no ELU
    gemm_att<32, 1><<<gb, 256, 0, stream>>>(feat, W2, as2, ad2, hbuf, a_s, a_d, n);
    aggregate<1, 32, false><<<ab, 256, 0, stream>>>(row_ptr, ssrc, hbuf, a_s, a_d, b2,
                                                    (float*)d_out, n);
}

// Round 10
// 283.162 us; speedup vs baseline: 4.3028x; 1.1611x over previous
//
#include <hip/hip_runtime.h>
#include <hip/hip_bf16.h>

// ---------------------------------------------------------------------------
// 3-layer GAT (PyG GATConv style) on MI355X.
// CSR build via two-level bucketed counting sort (bucket = dst>>6).
// Per layer: fused GEMM+attention-logits (bf16 feature table, fp32 logits),
// then wave-per-node edge-softmax + aggregate:
//   pass 1 = fmax sweep (LDS logit cache) + LDS exp sweep (fp32);
//   pass 2 = uint4 bf16-lane gather, 8 (or 16) edges per wave-iteration.
// Assumes n <= 65536 (src packed in 16 bits in the sort).
// ---------------------------------------------------------------------------

__device__ __forceinline__ float lrelu(float x) { return x > 0.f ? x : 0.2f * x; }
__device__ __forceinline__ float bflo(unsigned u) { return __uint_as_float(u << 16); }
__device__ __forceinline__ float bfhi(unsigned u) { return __uint_as_float(u & 0xFFFF0000u); }

#define PCHUNK 8192

// ---- CSR build ------------------------------------------------------------
__global__ __launch_bounds__(256) void bucket_count(const int* __restrict__ edges,
                                                    int E, int n, int NB,
                                                    int* __restrict__ bdeg) {
    __shared__ int hist[1024];
    for (int i = threadIdx.x; i < NB; i += 256) hist[i] = 0;
    __syncthreads();
    int EP = E + n;
    int stride = gridDim.x * blockDim.x;
    for (int e = blockIdx.x * blockDim.x + threadIdx.x; e < EP; e += stride) {
        int d = (e < E) ? edges[E + e] : (e - E);   // self-loop appended
        atomicAdd(&hist[d >> 6], 1);
    }
    __syncthreads();
    for (int i = threadIdx.x; i < NB; i += 256)
        if (hist[i]) atomicAdd(&bdeg[i], hist[i]);
}

__global__ __launch_bounds__(1024) void bucket_scan(const int* __restrict__ bdeg,
                                                    int* __restrict__ bstart,
                                                    int* __restrict__ bcursor,
                                                    int* __restrict__ row_ptr,
                                                    int NB, int n, int EP) {
    __shared__ int buf[1024];
    int tid = threadIdx.x;
    int v = (tid < NB) ? bdeg[tid] : 0;
    buf[tid] = v;
    __syncthreads();
    for (int off = 1; off < 1024; off <<= 1) {
        int t = (tid >= off) ? buf[tid - off] : 0;
        __syncthreads();
        buf[tid] += t;
        __syncthreads();
    }
    if (tid < NB) { bstart[tid] = buf[tid] - v; bcursor[tid] = buf[tid] - v; }
    if (tid == 0) { bstart[NB] = EP; row_ptr[n] = EP; }
}

__global__ __launch_bounds__(256) void partition(const int* __restrict__ edges,
                                                 int E, int n, int NB,
                                                 int* __restrict__ bcursor,
                                                 unsigned* __restrict__ T) {
    __shared__ int hist[1024];
    __shared__ int base[1024];
    int EP = E + n;
    int e0 = blockIdx.x * PCHUNK;
    int e1 = min(EP, e0 + PCHUNK);
    for (int i = threadIdx.x; i < NB; i += 256) hist[i] = 0;
    __syncthreads();
    for (int e = e0 + threadIdx.x; e < e1; e += 256) {
        int d = (e < E) ? edges[E + e] : (e - E);
        atomicAdd(&hist[d >> 6], 1);
    }
    __syncthreads();
    for (int i = threadIdx.x; i < NB; i += 256) {
        int c = hist[i];
        base[i] = c ? atomicAdd(&bcursor[i], c) : 0;
        hist[i] = 0;          // same thread owns this index in both loops
    }
    __syncthreads();
    for (int e = e0 + threadIdx.x; e < e1; e += 256) {
        int s, d;
        if (e < E) { s = edges[e]; d = edges[E + e]; }
        else       { s = e - E;    d = e - E; }
        int b = d >> 6;
        int r = atomicAdd(&hist[b], 1);
        T[base[b] + r] = (unsigned)s | ((unsigned)(d & 63) << 16);
    }
}

__global__ __launch_bounds__(256) void bucket_sort(const unsigned* __restrict__ T,
                                                   const int* __restrict__ bstart,
                                                   int n, int* __restrict__ row_ptr,
                                                   int* __restrict__ ssrc) {
    __shared__ int cnt[64];
    int b = blockIdx.x;
    int s0 = bstart[b], s1 = bstart[b + 1];
    int node0 = b << 6;
    if (threadIdx.x < 64) cnt[threadIdx.x] = 0;
    __syncthreads();
    for (int i = s0 + threadIdx.x; i < s1; i += 256)
        atomicAdd(&cnt[(T[i] >> 16) & 63], 1);
    __syncthreads();
    if (threadIdx.x < 64) {
        int v = cnt[threadIdx.x];
        int p = v;
        for (int o = 1; o < 64; o <<= 1) {
            int t = __shfl_up(p, o);
            if ((int)threadIdx.x >= o) p += t;
        }
        int excl = p - v;
        if (node0 + (int)threadIdx.x < n) row_ptr[node0 + threadIdx.x] = s0 + excl;
        cnt[threadIdx.x] = excl;          // reuse as running cursor
    }
    __syncthreads();
    for (int i = s0 + threadIdx.x; i < s1; i += 256) {
        unsigned t = T[i];
        int r = atomicAdd(&cnt[(t >> 16) & 63], 1);
        ssrc[s0 + r] = (int)(t & 0xFFFFu);
    }
}

// ---- fused h = X @ W (bf16 out) and per-node attention logits (fp32) ------
template <int OUT, int H>
__global__ __launch_bounds__(256) void gemm_att(const float* __restrict__ X,
                                                const float* __restrict__ W,
                                                const float* __restrict__ att_s,
                                                const float* __restrict__ att_d,
                                                __hip_bfloat16* __restrict__ Hout,
                                                float* __restrict__ a_src,
                                                float* __restrict__ a_dst, int n) {
    constexpr int C = OUT / H;
    __shared__ float xs[64][64];
    __shared__ float ws[64][OUT];
    int tid = threadIdx.x;
    int row0 = blockIdx.x * 64;
    for (int i = tid; i < 64 * OUT / 4; i += 256)
        ((float4*)&ws[0][0])[i] = ((const float4*)W)[i];
    for (int i = tid; i < 64 * 64 / 4; i += 256) {
        int r = (i * 4) / 64, c = (i * 4) % 64;
        int gr = row0 + r;
        float4 v = make_float4(0.f, 0.f, 0.f, 0.f);
        if (gr < n) v = ((const float4*)(X + (size_t)gr * 64))[c / 4];
        ((float4*)&xs[0][0])[i] = v;
    }
    __syncthreads();
    const int c = tid % OUT;
    const float asv = att_s[c], adv = att_d[c];   // (H,C) packed == [c]
    const int RSTEP = 256 / OUT;
    for (int r = tid / OUT; r < 64; r += RSTEP) {
        int gr = row0 + r;
        float acc = 0.f;
#pragma unroll
        for (int k = 0; k < 64; k++) acc += xs[r][k] * ws[k][c];
        float ts = acc * asv, td = acc * adv;     // logits from fp32 acc
#pragma unroll
        for (int mask = 1; mask < C; mask <<= 1) {
            ts += __shfl_xor(ts, mask);
            td += __shfl_xor(td, mask);
        }
        if (gr < n) {
            Hout[(size_t)gr * OUT + c] = __float2bfloat16(acc);
            if (c % C == 0) {
                a_src[(size_t)gr * H + c / C] = ts;
                a_dst[(size_t)gr * H + c / C] = td;
            }
        }
    }
}

// ---- wave-per-node softmax + aggregate (+bias, +optional ELU) -------------
template <int H, int C, bool DO_ELU>
__global__ __launch_bounds__(256) void aggregate(
    const int* __restrict__ row_ptr, const int* __restrict__ ssrc,
    const __hip_bfloat16* __restrict__ Hf, const float* __restrict__ a_src,
    const float* __restrict__ a_dst, const float* __restrict__ bias,
    float* __restrict__ Xout, int n) {
    constexpr int HC = H * C;
    constexpr int CAP = 128;                 // max cached edges per node
    constexpr int SLOTS = 64 / H;            // pass-1 edges per iteration
    constexpr int LPR = HC / 8;              // pass-2 lanes per row (8 bf16/lane)
    constexpr int EPG = 64 / LPR;            // pass-2 edges per iteration
    __shared__ float evbuf[4][CAP * H];

    int wid = (blockIdx.x * blockDim.x + threadIdx.x) >> 6;
    int lane = threadIdx.x & 63;
    int wv = threadIdx.x >> 6;
    bool live = wid < n;

    int start = 0, nloc = 0;
    if (live) { start = row_ptr[wid]; nloc = row_ptr[wid + 1] - start; }

    // ---- pass 1, sweep A: gather logits, cache in LDS, track max ----
    int hd = lane % H;
    int eg = lane / H;
    float m = -1e30f;
    float adst1 = live ? a_dst[(size_t)wid * H + hd] : 0.f;
    if (live) {
        for (int i = eg; i < nloc; i += SLOTS) {
            int s = ssrc[start + i];
            float ev = lrelu(a_src[(size_t)s * H + hd] + adst1);
            if (i < CAP) evbuf[wv][i * H + hd] = ev;
            m = fmaxf(m, ev);
        }
    }
#pragma unroll
    for (int mask = H; mask < 64; mask <<= 1) m = fmaxf(m, __shfl_xor(m, mask));

    // ---- pass 1, sweep B: sum of exp from the LDS cache ----
    float ssum = 0.f;
    if (live) {
        for (int i = eg; i < nloc; i += SLOTS) {
            float ev;
            if (i < CAP) ev = evbuf[wv][i * H + hd];
            else {
                int s = ssrc[start + i];
                ev = lrelu(a_src[(size_t)s * H + hd] + adst1);
            }
            ssum += __expf(ev - m);
        }
    }
#pragma unroll
    for (int mask = H; mask < 64; mask <<= 1) ssum += __shfl_xor(ssum, mask);
    float inv = 1.f / (ssum + 1e-16f);
    __syncthreads();                          // evbuf visible across lanes

    // ---- pass 2: bf16 uint4-lane weighted gather, EPG edges/iteration ----
    int lr = lane % LPR;                      // lane-in-row
    int sub = lane / LPR;                     // edge slot in group
    int head2 = (lr * 8) / C;                 // head owning channels lr*8..+7
    float m2 = __shfl(m, head2);              // lane h holds head h's merged m
    float inv2 = __shfl(inv, head2);
    float av[8];
#pragma unroll
    for (int k = 0; k < 8; k++) av[k] = 0.f;
    if (live) {
        float adst2 = a_dst[(size_t)wid * H + head2];
#pragma unroll 2
        for (int i = 0; i < nloc; i += EPG) {
            int ii = i + sub;
            float alpha = 0.f;
            int s = 0;
            if (ii < nloc) {
                s = ssrc[start + ii];
                float ev = (ii < CAP) ? evbuf[wv][ii * H + head2]
                                      : lrelu(a_src[(size_t)s * H + head2] + adst2);
                alpha = __expf(ev - m2) * inv2;
            }
            uint4 f = ((const uint4*)(Hf + (size_t)s * HC))[lr];
            av[0] += alpha * bflo(f.x); av[1] += alpha * bfhi(f.x);
            av[2] += alpha * bflo(f.y); av[3] += alpha * bfhi(f.y);
            av[4] += alpha * bflo(f.z); av[5] += alpha * bfhi(f.z);
            av[6] += alpha * bflo(f.w); av[7] += alpha * bfhi(f.w);
        }
    }
#pragma unroll
    for (int mask = LPR; mask < 64; mask <<= 1) {
#pragma unroll
        for (int k = 0; k < 8; k++) av[k] += __shfl_xor(av[k], mask);
    }
    if (live && lane < LPR) {
        float4 b0 = ((const float4*)bias)[lr * 2];
        float4 b1 = ((const float4*)bias)[lr * 2 + 1];
        float o[8];
        o[0] = av[0] + b0.x; o[1] = av[1] + b0.y; o[2] = av[2] + b0.z; o[3] = av[3] + b0.w;
        o[4] = av[4] + b1.x; o[5] = av[5] + b1.y; o[6] = av[6] + b1.z; o[7] = av[7] + b1.w;
        if (DO_ELU) {
#pragma unroll
            for (int k = 0; k < 8; k++) o[k] = o[k] > 0.f ? o[k] : (__expf(o[k]) - 1.f);
        }
        float4* outp = (float4*)(Xout + (size_t)wid * HC);
        outp[lr * 2]     = make_float4(o[0], o[1], o[2], o[3]);
        outp[lr * 2 + 1] = make_float4(o[4], o[5], o[6], o[7]);
    }
}

// ---------------------------------------------------------------------------
extern "C" void kernel_launch(void* const* d_in, const int* in_sizes, int n_in,
                              void* d_out, int out_size, void* d_ws, size_t ws_size,
                              hipStream_t stream) {
    const float* x     = (const float*)d_in[0];
    const int*   edges = (const int*)d_in[1];
    // d_in[2] = batch (unused)
    const float* W0 = (const float*)d_in[3];
    const float* as0 = (const float*)d_in[4];
    const float* ad0 = (const float*)d_in[5];
    const float* b0 = (const float*)d_in[6];
    const float* W1 = (const float*)d_in[7];
    const float* as1 = (const float*)d_in[8];
    const float* ad1 = (const float*)d_in[9];
    const float* b1 = (const float*)d_in[10];
    const float* W2 = (const float*)d_in[11];
    const float* as2 = (const float*)d_in[12];
    const float* ad2 = (const float*)d_in[13];
    const float* b2 = (const float*)d_in[14];

    const int n = in_sizes[0] / 64;
    const int E = in_sizes[1] / 2;
    const int EP = E + n;
    const int NB = (n + 63) >> 6;              // buckets (<=1024 for n<=65536)

    char* p = (char*)d_ws;
    auto alloc = [&](size_t bytes) {
        void* q = (void*)p;
        p += (bytes + 255) & ~(size_t)255;
        return q;
    };
    int*   bdeg    = (int*)alloc((size_t)NB * 4);
    int*   bstart  = (int*)alloc((size_t)(NB + 1) * 4);
    int*   bcursor = (int*)alloc((size_t)NB * 4);
    int*   row_ptr = (int*)alloc((size_t)(n + 1) * 4);
    int*   ssrc    = (int*)alloc((size_t)EP * 4);
    // hbuf (bf16 features) aliases the sort's temp array T; size = max of both.
    size_t hbytes = (size_t)n * 64 * 2;
    size_t tbytes = (size_t)EP * 4;
    void*  hraw   = alloc(hbytes > tbytes ? hbytes : tbytes);
    __hip_bfloat16* hbuf = (__hip_bfloat16*)hraw;
    unsigned*       T    = (unsigned*)hraw;    // consumed before first GEMM writes
    float* a_s     = (float*)alloc((size_t)n * 8 * 4);
    float* a_d     = (float*)alloc((size_t)n * 8 * 4);
    float* feat    = (float*)alloc((size_t)n * 64 * 4);
    (void)ws_size;

    hipMemsetAsync(bdeg, 0, (size_t)NB * 4, stream);
    bucket_count<<<256, 256, 0, stream>>>(edges, E, n, NB, bdeg);
    bucket_scan<<<1, 1024, 0, stream>>>(bdeg, bstart, bcursor, row_ptr, NB, n, EP);
    partition<<<(EP + PCHUNK - 1) / PCHUNK, 256, 0, stream>>>(edges, E, n, NB, bcursor, T);
    bucket_sort<<<NB, 256, 0, stream>>>(T, bstart, n, row_ptr, ssrc);

    int gb = (n + 63) / 64;       // gemm blocks
    int ab = (n + 3) / 4;         // aggregate blocks (4 waves/block)

    // Layer 0: 64 -> 8x8, concat, ELU
    gemm_att<64, 8><<<gb, 256, 0, stream>>>(x, W0, as0, ad0, hbuf, a_s, a_d, n);
    aggregate<8, 8, true><<<ab, 256, 0, stream>>>(row_ptr, ssrc, hbuf, a_s, a_d, b0, feat, n);

    // Layer 1: 64 -> 8x8, concat, ELU
    gemm_att<64, 8><<<gb, 256, 0, stream>>>(feat, W1, as1, ad1, hbuf, a_s, a_d, n);
    aggregate<8, 8, true><<<ab, 256, 0, stream>>>(row_ptr, ssrc, hbuf, a_s, a_d, b1, feat, n);

    // Layer 2: 64 -> 1x32, mean(=identity), no ELU
    gemm_att<32, 1><<<gb, 256, 0, stream>>>(feat, W2, as2, ad2, hbuf, a_s, a_d, n);
    aggregate<1, 32, false><<<ab, 256, 0, stream>>>(row_ptr, ssrc, hbuf, a_s, a_d, b2,
                                                    (float*)d_out, n);
}

// Round 12
// 273.609 us; speedup vs baseline: 4.4530x; 1.0349x over previous
//
#include <hip/hip_runtime.h>
#include <hip/hip_bf16.h>

// ---------------------------------------------------------------------------
// 3-layer GAT (PyG GATConv style) on MI355X.
// CSR build via two-level bucketed counting sort (bucket = dst>>6).
// Per layer: fused GEMM+attention-logits (bf16 feature table, fp32 logits),
// then wave-per-node edge-softmax + aggregate:
//   pass 1 = ONE sweep: p=exp(lrelu(e)) cached in LDS + butterfly sum
//            (no max subtraction: logits are O(1), exp cannot overflow fp32);
//   pass 2 = uint4 bf16-lane gather, alpha = p_LDS * inv, 8/16 edges per iter.
// Assumes n <= 65536 (src packed in 16 bits in the sort).
// ---------------------------------------------------------------------------

__device__ __forceinline__ float lrelu(float x) { return x > 0.f ? x : 0.2f * x; }
__device__ __forceinline__ float bflo(unsigned u) { return __uint_as_float(u << 16); }
__device__ __forceinline__ float bfhi(unsigned u) { return __uint_as_float(u & 0xFFFF0000u); }

#define PCHUNK 8192

// ---- CSR build ------------------------------------------------------------
__global__ __launch_bounds__(256) void bucket_count(const int* __restrict__ edges,
                                                    int E, int n, int NB,
                                                    int* __restrict__ bdeg) {
    __shared__ int hist[1024];
    for (int i = threadIdx.x; i < NB; i += 256) hist[i] = 0;
    __syncthreads();
    int EP = E + n;
    int stride = gridDim.x * blockDim.x;
    for (int e = blockIdx.x * blockDim.x + threadIdx.x; e < EP; e += stride) {
        int d = (e < E) ? edges[E + e] : (e - E);   // self-loop appended
        atomicAdd(&hist[d >> 6], 1);
    }
    __syncthreads();
    for (int i = threadIdx.x; i < NB; i += 256)
        if (hist[i]) atomicAdd(&bdeg[i], hist[i]);
}

__global__ __launch_bounds__(1024) void bucket_scan(const int* __restrict__ bdeg,
                                                    int* __restrict__ bstart,
                                                    int* __restrict__ bcursor,
                                                    int* __restrict__ row_ptr,
                                                    int NB, int n, int EP) {
    __shared__ int buf[1024];
    int tid = threadIdx.x;
    int v = (tid < NB) ? bdeg[tid] : 0;
    buf[tid] = v;
    __syncthreads();
    for (int off = 1; off < 1024; off <<= 1) {
        int t = (tid >= off) ? buf[tid - off] : 0;
        __syncthreads();
        buf[tid] += t;
        __syncthreads();
    }
    if (tid < NB) { bstart[tid] = buf[tid] - v; bcursor[tid] = buf[tid] - v; }
    if (tid == 0) { bstart[NB] = EP; row_ptr[n] = EP; }
}

__global__ __launch_bounds__(256) void partition(const int* __restrict__ edges,
                                                 int E, int n, int NB,
                                                 int* __restrict__ bcursor,
                                                 unsigned* __restrict__ T) {
    __shared__ int hist[1024];
    __shared__ int base[1024];
    int EP = E + n;
    int e0 = blockIdx.x * PCHUNK;
    int e1 = min(EP, e0 + PCHUNK);
    for (int i = threadIdx.x; i < NB; i += 256) hist[i] = 0;
    __syncthreads();
    for (int e = e0 + threadIdx.x; e < e1; e += 256) {
        int d = (e < E) ? edges[E + e] : (e - E);
        atomicAdd(&hist[d >> 6], 1);
    }
    __syncthreads();
    for (int i = threadIdx.x; i < NB; i += 256) {
        int c = hist[i];
        base[i] = c ? atomicAdd(&bcursor[i], c) : 0;
        hist[i] = 0;          // same thread owns this index in both loops
    }
    __syncthreads();
    for (int e = e0 + threadIdx.x; e < e1; e += 256) {
        int s, d;
        if (e < E) { s = edges[e]; d = edges[E + e]; }
        else       { s = e - E;    d = e - E; }
        int b = d >> 6;
        int r = atomicAdd(&hist[b], 1);
        T[base[b] + r] = (unsigned)s | ((unsigned)(d & 63) << 16);
    }
}

__global__ __launch_bounds__(256) void bucket_sort(const unsigned* __restrict__ T,
                                                   const int* __restrict__ bstart,
                                                   int n, int* __restrict__ row_ptr,
                                                   int* __restrict__ ssrc) {
    __shared__ int cnt[64];
    int b = blockIdx.x;
    int s0 = bstart[b], s1 = bstart[b + 1];
    int node0 = b << 6;
    if (threadIdx.x < 64) cnt[threadIdx.x] = 0;
    __syncthreads();
    for (int i = s0 + threadIdx.x; i < s1; i += 256)
        atomicAdd(&cnt[(T[i] >> 16) & 63], 1);
    __syncthreads();
    if (threadIdx.x < 64) {
        int v = cnt[threadIdx.x];
        int p = v;
        for (int o = 1; o < 64; o <<= 1) {
            int t = __shfl_up(p, o);
            if ((int)threadIdx.x >= o) p += t;
        }
        int excl = p - v;
        if (node0 + (int)threadIdx.x < n) row_ptr[node0 + threadIdx.x] = s0 + excl;
        cnt[threadIdx.x] = excl;          // reuse as running cursor
    }
    __syncthreads();
    for (int i = s0 + threadIdx.x; i < s1; i += 256) {
        unsigned t = T[i];
        int r = atomicAdd(&cnt[(t >> 16) & 63], 1);
        ssrc[s0 + r] = (int)(t & 0xFFFFu);
    }
}

// ---- fused h = X @ W (bf16 out) and per-node attention logits (fp32) ------
template <int OUT, int H>
__global__ __launch_bounds__(256) void gemm_att(const float* __restrict__ X,
                                                const float* __restrict__ W,
                                                const float* __restrict__ att_s,
                                                const float* __restrict__ att_d,
                                                __hip_bfloat16* __restrict__ Hout,
                                                float* __restrict__ a_src,
                                                float* __restrict__ a_dst, int n) {
    constexpr int C = OUT / H;
    __shared__ float xs[64][64];
    __shared__ float ws[64][OUT];
    int tid = threadIdx.x;
    int row0 = blockIdx.x * 64;
    for (int i = tid; i < 64 * OUT / 4; i += 256)
        ((float4*)&ws[0][0])[i] = ((const float4*)W)[i];
    for (int i = tid; i < 64 * 64 / 4; i += 256) {
        int r = (i * 4) / 64, c = (i * 4) % 64;
        int gr = row0 + r;
        float4 v = make_float4(0.f, 0.f, 0.f, 0.f);
        if (gr < n) v = ((const float4*)(X + (size_t)gr * 64))[c / 4];
        ((float4*)&xs[0][0])[i] = v;
    }
    __syncthreads();
    const int c = tid % OUT;
    const float asv = att_s[c], adv = att_d[c];   // (H,C) packed == [c]
    const int RSTEP = 256 / OUT;
    for (int r = tid / OUT; r < 64; r += RSTEP) {
        int gr = row0 + r;
        float acc = 0.f;
#pragma unroll
        for (int k = 0; k < 64; k++) acc += xs[r][k] * ws[k][c];
        float ts = acc * asv, td = acc * adv;     // logits from fp32 acc
#pragma unroll
        for (int mask = 1; mask < C; mask <<= 1) {
            ts += __shfl_xor(ts, mask);
            td += __shfl_xor(td, mask);
        }
        if (gr < n) {
            Hout[(size_t)gr * OUT + c] = __float2bfloat16(acc);
            if (c % C == 0) {
                a_src[(size_t)gr * H + c / C] = ts;
                a_dst[(size_t)gr * H + c / C] = td;
            }
        }
    }
}

// ---- wave-per-node softmax + aggregate (+bias, +optional ELU) -------------
template <int H, int C, bool DO_ELU>
__global__ __launch_bounds__(256) void aggregate(
    const int* __restrict__ row_ptr, const int* __restrict__ ssrc,
    const __hip_bfloat16* __restrict__ Hf, const float* __restrict__ a_src,
    const float* __restrict__ a_dst, const float* __restrict__ bias,
    float* __restrict__ Xout, int n) {
    constexpr int HC = H * C;
    constexpr int CAP = 128;                 // max cached edges per node
    constexpr int SLOTS = 64 / H;            // pass-1 edges per iteration
    constexpr int LPR = HC / 8;              // pass-2 lanes per row (8 bf16/lane)
    constexpr int EPG = 64 / LPR;            // pass-2 edges per iteration
    __shared__ float pbuf[4][CAP * H];       // cached p = exp(lrelu(e))

    int wid = (blockIdx.x * blockDim.x + threadIdx.x) >> 6;
    int lane = threadIdx.x & 63;
    int wv = threadIdx.x >> 6;
    bool live = wid < n;

    int start = 0, nloc = 0;
    if (live) { start = row_ptr[wid]; nloc = row_ptr[wid + 1] - start; }

    // ---- pass 1: single sweep, p = exp(lrelu(e)), cache + running sum ----
    int hd = lane % H;
    int eg = lane / H;
    float ssum = 0.f;
    if (live) {
        float adst1 = a_dst[(size_t)wid * H + hd];
        for (int i = eg; i < nloc; i += SLOTS) {
            int s = ssrc[start + i];
            float p = __expf(lrelu(a_src[(size_t)s * H + hd] + adst1));
            if (i < CAP) pbuf[wv][i * H + hd] = p;
            ssum += p;
        }
    }
#pragma unroll
    for (int mask = H; mask < 64; mask <<= 1) ssum += __shfl_xor(ssum, mask);
    float inv = 1.f / (ssum + 1e-16f);
    __syncthreads();                          // pbuf visible across lanes

    // ---- pass 2: bf16 uint4-lane weighted gather, EPG edges/iteration ----
    int lr = lane % LPR;                      // lane-in-row
    int sub = lane / LPR;                     // edge slot in group
    int head2 = (lr * 8) / C;                 // head owning channels lr*8..+7
    float inv2 = __shfl(inv, head2);          // lane h holds head h's sum
    float2 av[4];
#pragma unroll
    for (int k = 0; k < 4; k++) av[k] = make_float2(0.f, 0.f);
    if (live) {
#pragma unroll 2
        for (int i = 0; i < nloc; i += EPG) {
            int ii = i + sub;
            float alpha = 0.f;
            int s = 0;
            if (ii < nloc) {
                s = ssrc[start + ii];
                float p;
                if (ii < CAP) p = pbuf[wv][ii * H + head2];
                else {
                    float adst2 = a_dst[(size_t)wid * H + head2];
                    p = __expf(lrelu(a_src[(size_t)s * H + head2] + adst2));
                }
                alpha = p * inv2;
            }
            uint4 f = ((const uint4*)(Hf + (size_t)s * HC))[lr];
            av[0].x += alpha * bflo(f.x); av[0].y += alpha * bfhi(f.x);
            av[1].x += alpha * bflo(f.y); av[1].y += alpha * bfhi(f.y);
            av[2].x += alpha * bflo(f.z); av[2].y += alpha * bfhi(f.z);
            av[3].x += alpha * bflo(f.w); av[3].y += alpha * bfhi(f.w);
        }
    }
#pragma unroll
    for (int mask = LPR; mask < 64; mask <<= 1) {
#pragma unroll
        for (int k = 0; k < 4; k++) {
            av[k].x += __shfl_xor(av[k].x, mask);
            av[k].y += __shfl_xor(av[k].y, mask);
        }
    }
    if (live && lane < LPR) {
        float4 b0 = ((const float4*)bias)[lr * 2];
        float4 b1 = ((const float4*)bias)[lr * 2 + 1];
        float o[8];
        o[0] = av[0].x + b0.x; o[1] = av[0].y + b0.y;
        o[2] = av[1].x + b0.z; o[3] = av[1].y + b0.w;
        o[4] = av[2].x + b1.x; o[5] = av[2].y + b1.y;
        o[6] = av[3].x + b1.z; o[7] = av[3].y + b1.w;
        if (DO_ELU) {
#pragma unroll
            for (int k = 0; k < 8; k++) o[k] = o[k] > 0.f ? o[k] : (__expf(o[k]) - 1.f);
        }
        float4* outp = (float4*)(Xout + (size_t)wid * HC);
        outp[lr * 2]     = make_float4(o[0], o[1], o[2], o[3]);
        outp[lr * 2 + 1] = make_float4(o[4], o[5], o[6], o[7]);
    }
}

// ---------------------------------------------------------------------------
extern "C" void kernel_launch(void* const* d_in, const int* in_sizes, int n_in,
                              void* d_out, int out_size, void* d_ws, size_t ws_size,
                              hipStream_t stream) {
    const float* x     = (const float*)d_in[0];
    const int*   edges = (const int*)d_in[1];
    // d_in[2] = batch (unused)
    const float* W0 = (const float*)d_in[3];
    const float* as0 = (const float*)d_in[4];
    const float* ad0 = (const float*)d_in[5];
    const float* b0 = (const float*)d_in[6];
    const float* W1 = (const float*)d_in[7];
    const float* as1 = (const float*)d_in[8];
    const float* ad1 = (const float*)d_in[9];
    const float* b1 = (const float*)d_in[10];
    const float* W2 = (const float*)d_in[11];
    const float* as2 = (const float*)d_in[12];
    const float* ad2 = (const float*)d_in[13];
    const float* b2 = (const float*)d_in[14];

    const int n = in_sizes[0] / 64;
    const int E = in_sizes[1] / 2;
    const int EP = E + n;
    const int NB = (n + 63) >> 6;              // buckets (<=1024 for n<=65536)

    char* p = (char*)d_ws;
    auto alloc = [&](size_t bytes) {
        void* q = (void*)p;
        p += (bytes + 255) & ~(size_t)255;
        return q;
    };
    int*   bdeg    = (int*)alloc((size_t)NB * 4);
    int*   bstart  = (int*)alloc((size_t)(NB + 1) * 4);
    int*   bcursor = (int*)alloc((size_t)NB * 4);
    int*   row_ptr = (int*)alloc((size_t)(n + 1) * 4);
    int*   ssrc    = (int*)alloc((size_t)EP * 4);
    // hbuf (bf16 features) aliases the sort's temp array T; size = max of both.
    size_t hbytes = (size_t)n * 64 * 2;
    size_t tbytes = (size_t)EP * 4;
    void*  hraw   = alloc(hbytes > tbytes ? hbytes : tbytes);
    __hip_bfloat16* hbuf = (__hip_bfloat16*)hraw;
    unsigned*       T    = (unsigned*)hraw;    // consumed before first GEMM writes
    float* a_s     = (float*)alloc((size_t)n * 8 * 4);
    float* a_d     = (float*)alloc((size_t)n * 8 * 4);
    float* feat    = (float*)alloc((size_t)n * 64 * 4);
    (void)ws_size;

    hipMemsetAsync(bdeg, 0, (size_t)NB * 4, stream);
    bucket_count<<<256, 256, 0, stream>>>(edges, E, n, NB, bdeg);
    bucket_scan<<<1, 1024, 0, stream>>>(bdeg, bstart, bcursor, row_ptr, NB, n, EP);
    partition<<<(EP + PCHUNK - 1) / PCHUNK, 256, 0, stream>>>(edges, E, n, NB, bcursor, T);
    bucket_sort<<<NB, 256, 0, stream>>>(T, bstart, n, row_ptr, ssrc);

    int gb = (n + 63) / 64;       // gemm blocks
    int ab = (n + 3) / 4;         // aggregate blocks (4 waves/block)

    // Layer 0: 64 -> 8x8, concat, ELU
    gemm_att<64, 8><<<gb, 256, 0, stream>>>(x, W0, as0, ad0, hbuf, a_s, a_d, n);
    aggregate<8, 8, true><<<ab, 256, 0, stream>>>(row_ptr, ssrc, hbuf, a_s, a_d, b0, feat, n);

    // Layer 1: 64 -> 8x8, concat, ELU
    gemm_att<64, 8><<<gb, 256, 0, stream>>>(feat, W1, as1, ad1, hbuf, a_s, a_d, n);
    aggregate<8, 8, true><<<ab, 256, 0, stream>>>(row_ptr, ssrc, hbuf, a_s, a_d, b1, feat, n);

    // Layer 2: 64 -> 1x32, mean(=identity), no ELU
    gemm_att<32, 1><<<gb, 256, 0, stream>>>(feat, W2, as2, ad2, hbuf, a_s, a_d, n);
    aggregate<1, 32, false><<<ab, 256, 0, stream>>>(row_ptr, ssrc, hbuf, a_s, a_d, b2,
                                                    (float*)d_out, n);
}

// Round 13
// 261.057 us; speedup vs baseline: 4.6671x; 1.0481x over previous
//
#include <hip/hip_runtime.h>
#include <hip/hip_bf16.h>

// ---------------------------------------------------------------------------
// 3-layer GAT (PyG GATConv style) on MI355X.
// CSR build via two-level bucketed counting sort (bucket = dst>>6).
// Per layer: register-tiled fused GEMM+attention-logits (bf16 feature table,
// fp32 logits), then wave-per-node SINGLE-SWEEP softmax-aggregate:
//   acc += p*h and ssum += p in one loop (p = exp(lrelu(e)), no max needed:
//   logits are O(1)); normalize by 1/(ssum+eps) after a sub-lane butterfly.
// No LDS in aggregate. Assumes n <= 65536 (src packed in 16 bits in sort).
// ---------------------------------------------------------------------------

__device__ __forceinline__ float lrelu(float x) { return x > 0.f ? x : 0.2f * x; }
__device__ __forceinline__ float bflo(unsigned u) { return __uint_as_float(u << 16); }
__device__ __forceinline__ float bfhi(unsigned u) { return __uint_as_float(u & 0xFFFF0000u); }

#define PCHUNK 8192

// ---- CSR build ------------------------------------------------------------
__global__ __launch_bounds__(256) void bucket_count(const int* __restrict__ edges,
                                                    int E, int n, int NB,
                                                    int* __restrict__ bdeg) {
    __shared__ int hist[1024];
    for (int i = threadIdx.x; i < NB; i += 256) hist[i] = 0;
    __syncthreads();
    int EP = E + n;
    int stride = gridDim.x * blockDim.x;
    for (int e = blockIdx.x * blockDim.x + threadIdx.x; e < EP; e += stride) {
        int d = (e < E) ? edges[E + e] : (e - E);   // self-loop appended
        atomicAdd(&hist[d >> 6], 1);
    }
    __syncthreads();
    for (int i = threadIdx.x; i < NB; i += 256)
        if (hist[i]) atomicAdd(&bdeg[i], hist[i]);
}

__global__ __launch_bounds__(1024) void bucket_scan(const int* __restrict__ bdeg,
                                                    int* __restrict__ bstart,
                                                    int* __restrict__ bcursor,
                                                    int* __restrict__ row_ptr,
                                                    int NB, int n, int EP) {
    __shared__ int buf[1024];
    int tid = threadIdx.x;
    int v = (tid < NB) ? bdeg[tid] : 0;
    buf[tid] = v;
    __syncthreads();
    for (int off = 1; off < 1024; off <<= 1) {
        int t = (tid >= off) ? buf[tid - off] : 0;
        __syncthreads();
        buf[tid] += t;
        __syncthreads();
    }
    if (tid < NB) { bstart[tid] = buf[tid] - v; bcursor[tid] = buf[tid] - v; }
    if (tid == 0) { bstart[NB] = EP; row_ptr[n] = EP; }
}

__global__ __launch_bounds__(256) void partition(const int* __restrict__ edges,
                                                 int E, int n, int NB,
                                                 int* __restrict__ bcursor,
                                                 unsigned* __restrict__ T) {
    __shared__ int hist[1024];
    __shared__ int base[1024];
    int EP = E + n;
    int e0 = blockIdx.x * PCHUNK;
    int e1 = min(EP, e0 + PCHUNK);
    for (int i = threadIdx.x; i < NB; i += 256) hist[i] = 0;
    __syncthreads();
    for (int e = e0 + threadIdx.x; e < e1; e += 256) {
        int d = (e < E) ? edges[E + e] : (e - E);
        atomicAdd(&hist[d >> 6], 1);
    }
    __syncthreads();
    for (int i = threadIdx.x; i < NB; i += 256) {
        int c = hist[i];
        base[i] = c ? atomicAdd(&bcursor[i], c) : 0;
        hist[i] = 0;          // same thread owns this index in both loops
    }
    __syncthreads();
    for (int e = e0 + threadIdx.x; e < e1; e += 256) {
        int s, d;
        if (e < E) { s = edges[e]; d = edges[E + e]; }
        else       { s = e - E;    d = e - E; }
        int b = d >> 6;
        int r = atomicAdd(&hist[b], 1);
        T[base[b] + r] = (unsigned)s | ((unsigned)(d & 63) << 16);
    }
}

__global__ __launch_bounds__(256) void bucket_sort(const unsigned* __restrict__ T,
                                                   const int* __restrict__ bstart,
                                                   int n, int* __restrict__ row_ptr,
                                                   int* __restrict__ ssrc) {
    __shared__ int cnt[64];
    int b = blockIdx.x;
    int s0 = bstart[b], s1 = bstart[b + 1];
    int node0 = b << 6;
    if (threadIdx.x < 64) cnt[threadIdx.x] = 0;
    __syncthreads();
    for (int i = s0 + threadIdx.x; i < s1; i += 256)
        atomicAdd(&cnt[(T[i] >> 16) & 63], 1);
    __syncthreads();
    if (threadIdx.x < 64) {
        int v = cnt[threadIdx.x];
        int p = v;
        for (int o = 1; o < 64; o <<= 1) {
            int t = __shfl_up(p, o);
            if ((int)threadIdx.x >= o) p += t;
        }
        int excl = p - v;
        if (node0 + (int)threadIdx.x < n) row_ptr[node0 + threadIdx.x] = s0 + excl;
        cnt[threadIdx.x] = excl;          // reuse as running cursor
    }
    __syncthreads();
    for (int i = s0 + threadIdx.x; i < s1; i += 256) {
        unsigned t = T[i];
        int r = atomicAdd(&cnt[(t >> 16) & 63], 1);
        ssrc[s0 + r] = (int)(t & 0xFFFFu);
    }
}

// ---- register-tiled fused h = X @ W (bf16 out) + attention logits ---------
// Thread owns 4 strided cols {cg + j*CG} x RPT rows; 4x4 dot-tile per k-quad.
// Pitch-68 LDS: conflict-free float4 reads (bank stride 4 across lanes).
template <int OUT, int H>
__global__ __launch_bounds__(256) void gemm_att(const float* __restrict__ X,
                                                const float* __restrict__ W,
                                                const float* __restrict__ att_s,
                                                const float* __restrict__ att_d,
                                                __hip_bfloat16* __restrict__ Hout,
                                                float* __restrict__ a_src,
                                                float* __restrict__ a_dst, int n) {
    constexpr int C = OUT / H;
    constexpr int CG = OUT / 4;          // col groups: 16 (OUT=64), 8 (OUT=32)
    constexpr int RG = 256 / CG;         // row groups: 16, 32
    constexpr int RPT = 64 / RG;         // rows per thread: 4, 2
    constexpr int P = 68;                // LDS pitch (floats)
    __shared__ float xs[64][P];
    __shared__ float wsT[OUT][P];
    int tid = threadIdx.x;
    int row0 = blockIdx.x * 64;
    // stage W transposed (wsT[c][k] = W[k*OUT+c])
    for (int i = tid; i < 64 * OUT / 4; i += 256) {
        int k = (i * 4) / OUT, c = (i * 4) % OUT;
        float4 v = ((const float4*)W)[i];
        wsT[c][k] = v.x; wsT[c + 1][k] = v.y; wsT[c + 2][k] = v.z; wsT[c + 3][k] = v.w;
    }
    // stage X rows
    for (int i = tid; i < 64 * 16; i += 256) {
        int r = i / 16, c4 = i % 16;
        int gr = row0 + r;
        float4 v = make_float4(0.f, 0.f, 0.f, 0.f);
        if (gr < n) v = ((const float4*)(X + (size_t)gr * 64))[c4];
        *(float4*)&xs[r][c4 * 4] = v;
    }
    __syncthreads();
    const int cg = tid % CG, rg = tid / CG;
    float acc[RPT][4];
#pragma unroll
    for (int r = 0; r < RPT; r++)
#pragma unroll
        for (int j = 0; j < 4; j++) acc[r][j] = 0.f;
    for (int k = 0; k < 64; k += 4) {
        float4 wv[4];
#pragma unroll
        for (int j = 0; j < 4; j++) wv[j] = *(const float4*)&wsT[cg + j * CG][k];
#pragma unroll
        for (int r = 0; r < RPT; r++) {
            float4 xv = *(const float4*)&xs[rg + r * RG][k];
#pragma unroll
            for (int j = 0; j < 4; j++)
                acc[r][j] += xv.x * wv[j].x + xv.y * wv[j].y +
                             xv.z * wv[j].z + xv.w * wv[j].w;
        }
    }
#pragma unroll
    for (int r = 0; r < RPT; r++) {
        int gr = row0 + rg + r * RG;
        bool ok = gr < n;
#pragma unroll
        for (int j = 0; j < 4; j++) {
            int col = cg + j * CG;
            if (ok) Hout[(size_t)gr * OUT + col] = __float2bfloat16(acc[r][j]);
        }
        if constexpr (C <= CG) {
            // each j covers CG consecutive cols = CG/C heads; groups of C cgs
#pragma unroll
            for (int j = 0; j < 4; j++) {
                int col = cg + j * CG;
                float ts = acc[r][j] * att_s[col];
                float td = acc[r][j] * att_d[col];
#pragma unroll
                for (int m = 1; m < C; m <<= 1) {
                    ts += __shfl_xor(ts, m);
                    td += __shfl_xor(td, m);
                }
                if (ok && (cg % C) == 0) {
                    a_src[(size_t)gr * H + col / C] = ts;
                    a_dst[(size_t)gr * H + col / C] = td;
                }
            }
        } else {  // single head spans all cols (OUT=32, H=1)
            float ts = 0.f, td = 0.f;
#pragma unroll
            for (int j = 0; j < 4; j++) {
                int col = cg + j * CG;
                ts += acc[r][j] * att_s[col];
                td += acc[r][j] * att_d[col];
            }
#pragma unroll
            for (int m = 1; m < CG; m <<= 1) {
                ts += __shfl_xor(ts, m);
                td += __shfl_xor(td, m);
            }
            if (ok && cg == 0) { a_src[gr] = ts; a_dst[gr] = td; }
        }
    }
}

// ---- wave-per-node SINGLE-SWEEP softmax + aggregate (+bias, +opt ELU) -----
// Lane (sub,lr): 8 bf16 channels of head (lr*8)/C; per edge: gather a_src,
// p = exp(lrelu(e)), acc += p*h, ssum += p. Normalize after butterfly.
template <int H, int C, bool DO_ELU>
__global__ __launch_bounds__(256) void aggregate(
    const int* __restrict__ row_ptr, const int* __restrict__ ssrc,
    const __hip_bfloat16* __restrict__ Hf, const float* __restrict__ a_src,
    const float* __restrict__ a_dst, const float* __restrict__ bias,
    float* __restrict__ Xout, int n) {
    constexpr int HC = H * C;
    constexpr int LPR = HC / 8;          // lanes per row: 8 (HC=64), 4 (HC=32)
    constexpr int EPG = 64 / LPR;        // edges per iter: 8 or 16
    int wid = (blockIdx.x * blockDim.x + threadIdx.x) >> 6;
    if (wid >= n) return;                // wave-uniform; no barriers here
    int lane = threadIdx.x & 63;
    int lr = lane % LPR;
    int sub = lane / LPR;
    int head = (lr * 8) / C;             // HC=64: lr; HC=32: 0
    int start = row_ptr[wid];
    int nloc = row_ptr[wid + 1] - start;
    float adst = a_dst[(size_t)wid * H + head];
    float ssum = 0.f;
    float2 av[4];
#pragma unroll
    for (int k = 0; k < 4; k++) av[k] = make_float2(0.f, 0.f);
#pragma unroll 2
    for (int i = sub; i < nloc; i += EPG) {
        int s = ssrc[start + i];
        float p = __expf(lrelu(a_src[(size_t)s * H + head] + adst));
        ssum += p;
        uint4 f = ((const uint4*)(Hf + (size_t)s * HC))[lr];
        av[0].x += p * bflo(f.x); av[0].y += p * bfhi(f.x);
        av[1].x += p * bflo(f.y); av[1].y += p * bfhi(f.y);
        av[2].x += p * bflo(f.z); av[2].y += p * bfhi(f.z);
        av[3].x += p * bflo(f.w); av[3].y += p * bfhi(f.w);
    }
    // butterfly over sub-slices (fixed lr): per-head ssum + channel sums
#pragma unroll
    for (int mask = LPR; mask < 64; mask <<= 1) {
        ssum += __shfl_xor(ssum, mask);
#pragma unroll
        for (int k = 0; k < 4; k++) {
            av[k].x += __shfl_xor(av[k].x, mask);
            av[k].y += __shfl_xor(av[k].y, mask);
        }
    }
    if (lane < LPR) {
        float inv = 1.f / (ssum + 1e-16f);
        float4 b0 = ((const float4*)bias)[lr * 2];
        float4 b1 = ((const float4*)bias)[lr * 2 + 1];
        float o[8];
        o[0] = av[0].x * inv + b0.x; o[1] = av[0].y * inv + b0.y;
        o[2] = av[1].x * inv + b0.z; o[3] = av[1].y * inv + b0.w;
        o[4] = av[2].x * inv + b1.x; o[5] = av[2].y * inv + b1.y;
        o[6] = av[3].x * inv + b1.z; o[7] = av[3].y * inv + b1.w;
        if (DO_ELU) {
#pragma unroll
            for (int k = 0; k < 8; k++) o[k] = o[k] > 0.f ? o[k] : (__expf(o[k]) - 1.f);
        }
        float4* outp = (float4*)(Xout + (size_t)wid * HC);
        outp[lr * 2]     = make_float4(o[0], o[1], o[2], o[3]);
        outp[lr * 2 + 1] = make_float4(o[4], o[5], o[6], o[7]);
    }
}

// ---------------------------------------------------------------------------
extern "C" void kernel_launch(void* const* d_in, const int* in_sizes, int n_in,
                              void* d_out, int out_size, void* d_ws, size_t ws_size,
                              hipStream_t stream) {
    const float* x     = (const float*)d_in[0];
    const int*   edges = (const int*)d_in[1];
    // d_in[2] = batch (unused)
    const float* W0 = (const float*)d_in[3];
    const float* as0 = (const float*)d_in[4];
    const float* ad0 = (const float*)d_in[5];
    const float* b0 = (const float*)d_in[6];
    const float* W1 = (const float*)d_in[7];
    const float* as1 = (const float*)d_in[8];
    const float* ad1 = (const float*)d_in[9];
    const float* b1 = (const float*)d_in[10];
    const float* W2 = (const float*)d_in[11];
    const float* as2 = (const float*)d_in[12];
    const float* ad2 = (const float*)d_in[13];
    const float* b2 = (const float*)d_in[14];

    const int n = in_sizes[0] / 64;
    const int E = in_sizes[1] / 2;
    const int EP = E + n;
    const int NB = (n + 63) >> 6;              // buckets (<=1024 for n<=65536)

    char* p = (char*)d_ws;
    auto alloc = [&](size_t bytes) {
        void* q = (void*)p;
        p += (bytes + 255) & ~(size_t)255;
        return q;
    };
    int*   bdeg    = (int*)alloc((size_t)NB * 4);
    int*   bstart  = (int*)alloc((size_t)(NB + 1) * 4);
    int*   bcursor = (int*)alloc((size_t)NB * 4);
    int*   row_ptr = (int*)alloc((size_t)(n + 1) * 4);
    int*   ssrc    = (int*)alloc((size_t)EP * 4);
    // hbuf (bf16 features) aliases the sort's temp array T; size = max of both.
    size_t hbytes = (size_t)n * 64 * 2;
    size_t tbytes = (size_t)EP * 4;
    void*  hraw   = alloc(hbytes > tbytes ? hbytes : tbytes);
    __hip_bfloat16* hbuf = (__hip_bfloat16*)hraw;
    unsigned*       T    = (unsigned*)hraw;    // consumed before first GEMM writes
    float* a_s     = (float*)alloc((size_t)n * 8 * 4);
    float* a_d     = (float*)alloc((size_t)n * 8 * 4);
    float* feat    = (float*)alloc((size_t)n * 64 * 4);
    (void)ws_size;

    hipMemsetAsync(bdeg, 0, (size_t)NB * 4, stream);
    bucket_count<<<256, 256, 0, stream>>>(edges, E, n, NB, bdeg);
    bucket_scan<<<1, 1024, 0, stream>>>(bdeg, bstart, bcursor, row_ptr, NB, n, EP);
    partition<<<(EP + PCHUNK - 1) / PCHUNK, 256, 0, stream>>>(edges, E, n, NB, bcursor, T);
    bucket_sort<<<NB, 256, 0, stream>>>(T, bstart, n, row_ptr, ssrc);

    int gb = (n + 63) / 64;       // gemm blocks
    int ab = (n + 3) / 4;         // aggregate blocks (4 waves/block)

    // Layer 0: 64 -> 8x8, concat, ELU
    gemm_att<64, 8><<<gb, 256, 0, stream>>>(x, W0, as0, ad0, hbuf, a_s, a_d, n);
    aggregate<8, 8, true><<<ab, 256, 0, stream>>>(row_ptr, ssrc, hbuf, a_s, a_d, b0, feat, n);

    // Layer 1: 64 -> 8x8, concat, ELU
    gemm_att<64, 8><<<gb, 256, 0, stream>>>(feat, W1, as1, ad1, hbuf, a_s, a_d, n);
    aggregate<8, 8, true><<<ab, 256, 0, stream>>>(row_ptr, ssrc, hbuf, a_s, a_d, b1, feat, n);

    // Layer 2: 64 -> 1x32, mean(=identity), no ELU
    gemm_att<32, 1><<<gb, 256, 0, stream>>>(feat, W2, as2, ad2, hbuf, a_s, a_d, n);
    aggregate<1, 32, false><<<ab, 256, 0, stream>>>(row_ptr, ssrc, hbuf, a_s, a_d, b2,
                                                    (float*)d_out, n);
}

// Round 14
// 212.484 us; speedup vs baseline: 5.7340x; 1.2286x over previous
//
#include <hip/hip_runtime.h>
#include <hip/hip_bf16.h>

// ---------------------------------------------------------------------------
// 3-layer GAT (PyG GATConv style) on MI355X.
// CSR build via two-level bucketed counting sort (bucket = dst>>6).
// Per layer: fused GEMM+attention-logits (bf16 feature table, fp32 logits;
// thread = one float4 of cols per row-pass, W staged untransposed), then
// wave-per-node SINGLE-SWEEP softmax-aggregate (no LDS, no barrier):
//   acc += p*h, ssum += p in one loop (p = exp(lrelu(e)); no max needed:
//   logits are O(1)); normalize by 1/(ssum+eps) after a sub-lane butterfly.
// Assumes n <= 65536 (src packed in 16 bits in sort).
// ---------------------------------------------------------------------------

__device__ __forceinline__ float lrelu(float x) { return x > 0.f ? x : 0.2f * x; }
__device__ __forceinline__ float bflo(unsigned u) { return __uint_as_float(u << 16); }
__device__ __forceinline__ float bfhi(unsigned u) { return __uint_as_float(u & 0xFFFF0000u); }
__device__ __forceinline__ unsigned bfpack(float lo, float hi) {
    __hip_bfloat16 a = __float2bfloat16(lo), b = __float2bfloat16(hi);
    unsigned short ua = *(unsigned short*)&a, ub = *(unsigned short*)&b;
    return (unsigned)ua | ((unsigned)ub << 16);
}

#define PCHUNK 8192

// ---- CSR build ------------------------------------------------------------
__global__ __launch_bounds__(256) void bucket_count(const int* __restrict__ edges,
                                                    int E, int n, int NB,
                                                    int* __restrict__ bdeg) {
    __shared__ int hist[1024];
    for (int i = threadIdx.x; i < NB; i += 256) hist[i] = 0;
    __syncthreads();
    int EP = E + n;
    int stride = gridDim.x * blockDim.x;
    for (int e = blockIdx.x * blockDim.x + threadIdx.x; e < EP; e += stride) {
        int d = (e < E) ? edges[E + e] : (e - E);   // self-loop appended
        atomicAdd(&hist[d >> 6], 1);
    }
    __syncthreads();
    for (int i = threadIdx.x; i < NB; i += 256)
        if (hist[i]) atomicAdd(&bdeg[i], hist[i]);
}

__global__ __launch_bounds__(1024) void bucket_scan(const int* __restrict__ bdeg,
                                                    int* __restrict__ bstart,
                                                    int* __restrict__ bcursor,
                                                    int* __restrict__ row_ptr,
                                                    int NB, int n, int EP) {
    __shared__ int buf[1024];
    int tid = threadIdx.x;
    int v = (tid < NB) ? bdeg[tid] : 0;
    buf[tid] = v;
    __syncthreads();
    for (int off = 1; off < 1024; off <<= 1) {
        int t = (tid >= off) ? buf[tid - off] : 0;
        __syncthreads();
        buf[tid] += t;
        __syncthreads();
    }
    if (tid < NB) { bstart[tid] = buf[tid] - v; bcursor[tid] = buf[tid] - v; }
    if (tid == 0) { bstart[NB] = EP; row_ptr[n] = EP; }
}

__global__ __launch_bounds__(256) void partition(const int* __restrict__ edges,
                                                 int E, int n, int NB,
                                                 int* __restrict__ bcursor,
                                                 unsigned* __restrict__ T) {
    __shared__ int hist[1024];
    __shared__ int base[1024];
    int EP = E + n;
    int e0 = blockIdx.x * PCHUNK;
    int e1 = min(EP, e0 + PCHUNK);
    for (int i = threadIdx.x; i < NB; i += 256) hist[i] = 0;
    __syncthreads();
    for (int e = e0 + threadIdx.x; e < e1; e += 256) {
        int d = (e < E) ? edges[E + e] : (e - E);
        atomicAdd(&hist[d >> 6], 1);
    }
    __syncthreads();
    for (int i = threadIdx.x; i < NB; i += 256) {
        int c = hist[i];
        base[i] = c ? atomicAdd(&bcursor[i], c) : 0;
        hist[i] = 0;          // same thread owns this index in both loops
    }
    __syncthreads();
    for (int e = e0 + threadIdx.x; e < e1; e += 256) {
        int s, d;
        if (e < E) { s = edges[e]; d = edges[E + e]; }
        else       { s = e - E;    d = e - E; }
        int b = d >> 6;
        int r = atomicAdd(&hist[b], 1);
        T[base[b] + r] = (unsigned)s | ((unsigned)(d & 63) << 16);
    }
}

__global__ __launch_bounds__(256) void bucket_sort(const unsigned* __restrict__ T,
                                                   const int* __restrict__ bstart,
                                                   int n, int* __restrict__ row_ptr,
                                                   int* __restrict__ ssrc) {
    __shared__ int cnt[64];
    int b = blockIdx.x;
    int s0 = bstart[b], s1 = bstart[b + 1];
    int node0 = b << 6;
    if (threadIdx.x < 64) cnt[threadIdx.x] = 0;
    __syncthreads();
    for (int i = s0 + threadIdx.x; i < s1; i += 256)
        atomicAdd(&cnt[(T[i] >> 16) & 63], 1);
    __syncthreads();
    if (threadIdx.x < 64) {
        int v = cnt[threadIdx.x];
        int p = v;
        for (int o = 1; o < 64; o <<= 1) {
            int t = __shfl_up(p, o);
            if ((int)threadIdx.x >= o) p += t;
        }
        int excl = p - v;
        if (node0 + (int)threadIdx.x < n) row_ptr[node0 + threadIdx.x] = s0 + excl;
        cnt[threadIdx.x] = excl;          // reuse as running cursor
    }
    __syncthreads();
    for (int i = s0 + threadIdx.x; i < s1; i += 256) {
        unsigned t = T[i];
        int r = atomicAdd(&cnt[(t >> 16) & 63], 1);
        ssrc[s0 + r] = (int)(t & 0xFFFFu);
    }
}

// ---- fused h = X @ W (bf16 out) + attention logits (fp32) -----------------
// Thread owns float4 of cols c4 of one row per pass; per k: 1 broadcast xs
// read + 1 ws float4 read -> 4 FMAs. W staged untransposed (row-major = [k][c]).
template <int OUT, int H>
__global__ __launch_bounds__(256) void gemm_att(const float* __restrict__ X,
                                                const float* __restrict__ W,
                                                const float* __restrict__ att_s,
                                                const float* __restrict__ att_d,
                                                __hip_bfloat16* __restrict__ Hout,
                                                float* __restrict__ a_src,
                                                float* __restrict__ a_dst, int n) {
    constexpr int C = OUT / H;
    constexpr int CG = OUT / 4;          // col float4-groups: 16 (64), 8 (32)
    constexpr int RPP = 256 / CG;        // rows per pass: 16, 32
    constexpr int NPASS = 64 / RPP;      // 4, 2
    constexpr int L = C / 4;             // lanes per head: 2 (C=8), 8 (C=32)
    constexpr int PX = 68;               // xs pitch (floats)
    __shared__ float  xs[64][PX];
    __shared__ float4 ws4[64][CG];
    int tid = threadIdx.x;
    int row0 = blockIdx.x * 64;
    for (int i = tid; i < 64 * CG; i += 256)
        ws4[i / CG][i % CG] = ((const float4*)W)[i];
    for (int i = tid; i < 64 * 16; i += 256) {
        int r = i / 16, c4 = i % 16;
        int gr = row0 + r;
        float4 v = make_float4(0.f, 0.f, 0.f, 0.f);
        if (gr < n) v = ((const float4*)(X + (size_t)gr * 64))[c4];
        *(float4*)&xs[r][c4 * 4] = v;
    }
    __syncthreads();
    const int c4 = tid % CG;
    const int r_in = tid / CG;
    const float4 as4 = ((const float4*)att_s)[c4];
    const float4 ad4 = ((const float4*)att_d)[c4];
#pragma unroll
    for (int pass = 0; pass < NPASS; pass++) {
        int r = r_in + pass * RPP;
        int gr = row0 + r;
        float4 acc = make_float4(0.f, 0.f, 0.f, 0.f);
#pragma unroll
        for (int k = 0; k < 64; k++) {
            float xv = xs[r][k];
            float4 wv = ws4[k][c4];
            acc.x += xv * wv.x; acc.y += xv * wv.y;
            acc.z += xv * wv.z; acc.w += xv * wv.w;
        }
        bool ok = gr < n;
        if (ok) {
            uint2 packed = make_uint2(bfpack(acc.x, acc.y), bfpack(acc.z, acc.w));
            *(uint2*)(Hout + (size_t)gr * OUT + c4 * 4) = packed;
        }
        float ts = acc.x * as4.x + acc.y * as4.y + acc.z * as4.z + acc.w * as4.w;
        float td = acc.x * ad4.x + acc.y * ad4.y + acc.z * ad4.z + acc.w * ad4.w;
#pragma unroll
        for (int m = 1; m < L; m <<= 1) {
            ts += __shfl_xor(ts, m);
            td += __shfl_xor(td, m);
        }
        if (ok && (c4 % L) == 0) {
            int head = (c4 * 4) / C;
            a_src[(size_t)gr * H + head] = ts;
            a_dst[(size_t)gr * H + head] = td;
        }
    }
}

// ---- wave-per-node SINGLE-SWEEP softmax + aggregate (+bias, +opt ELU) -----
template <int H, int C, bool DO_ELU>
__global__ __launch_bounds__(256) void aggregate(
    const int* __restrict__ row_ptr, const int* __restrict__ ssrc,
    const __hip_bfloat16* __restrict__ Hf, const float* __restrict__ a_src,
    const float* __restrict__ a_dst, const float* __restrict__ bias,
    float* __restrict__ Xout, int n) {
    constexpr int HC = H * C;
    constexpr int LPR = HC / 8;          // lanes per row: 8 (HC=64), 4 (HC=32)
    constexpr int EPG = 64 / LPR;        // edges per iter: 8 or 16
    int wid = (blockIdx.x * blockDim.x + threadIdx.x) >> 6;
    if (wid >= n) return;                // wave-uniform; no barriers here
    int lane = threadIdx.x & 63;
    int lr = lane % LPR;
    int sub = lane / LPR;
    int head = (lr * 8) / C;             // HC=64: lr; HC=32: 0
    int start = row_ptr[wid];
    int nloc = row_ptr[wid + 1] - start;
    float adst = a_dst[(size_t)wid * H + head];
    float ssum = 0.f;
    float2 av[4];
#pragma unroll
    for (int k = 0; k < 4; k++) av[k] = make_float2(0.f, 0.f);
#pragma unroll 2
    for (int i = sub; i < nloc; i += EPG) {
        int s = ssrc[start + i];
        float p = __expf(lrelu(a_src[(size_t)s * H + head] + adst));
        ssum += p;
        uint4 f = ((const uint4*)(Hf + (size_t)s * HC))[lr];
        av[0].x += p * bflo(f.x); av[0].y += p * bfhi(f.x);
        av[1].x += p * bflo(f.y); av[1].y += p * bfhi(f.y);
        av[2].x += p * bflo(f.z); av[2].y += p * bfhi(f.z);
        av[3].x += p * bflo(f.w); av[3].y += p * bfhi(f.w);
    }
#pragma unroll
    for (int mask = LPR; mask < 64; mask <<= 1) {
        ssum += __shfl_xor(ssum, mask);
#pragma unroll
        for (int k = 0; k < 4; k++) {
            av[k].x += __shfl_xor(av[k].x, mask);
            av[k].y += __shfl_xor(av[k].y, mask);
        }
    }
    if (lane < LPR) {
        float inv = 1.f / (ssum + 1e-16f);
        float4 b0 = ((const float4*)bias)[lr * 2];
        float4 b1 = ((const float4*)bias)[lr * 2 + 1];
        float o[8];
        o[0] = av[0].x * inv + b0.x; o[1] = av[0].y * inv + b0.y;
        o[2] = av[1].x * inv + b0.z; o[3] = av[1].y * inv + b0.w;
        o[4] = av[2].x * inv + b1.x; o[5] = av[2].y * inv + b1.y;
        o[6] = av[3].x * inv + b1.z; o[7] = av[3].y * inv + b1.w;
        if (DO_ELU) {
#pragma unroll
            for (int k = 0; k < 8; k++) o[k] = o[k] > 0.f ? o[k] : (__expf(o[k]) - 1.f);
        }
        float4* outp = (float4*)(Xout + (size_t)wid * HC);
        outp[lr * 2]     = make_float4(o[0], o[1], o[2], o[3]);
        outp[lr * 2 + 1] = make_float4(o[4], o[5], o[6], o[7]);
    }
}

// ---------------------------------------------------------------------------
extern "C" void kernel_launch(void* const* d_in, const int* in_sizes, int n_in,
                              void* d_out, int out_size, void* d_ws, size_t ws_size,
                              hipStream_t stream) {
    const float* x     = (const float*)d_in[0];
    const int*   edges = (const int*)d_in[1];
    // d_in[2] = batch (unused)
    const float* W0 = (const float*)d_in[3];
    const float* as0 = (const float*)d_in[4];
    const float* ad0 = (const float*)d_in[5];
    const float* b0 = (const float*)d_in[6];
    const float* W1 = (const float*)d_in[7];
    const float* as1 = (const float*)d_in[8];
    const float* ad1 = (const float*)d_in[9];
    const float* b1 = (const float*)d_in[10];
    const float* W2 = (const float*)d_in[11];
    const float* as2 = (const float*)d_in[12];
    const float* ad2 = (const float*)d_in[13];
    const float* b2 = (const float*)d_in[14];

    const int n = in_sizes[0] / 64;
    const int E = in_sizes[1] / 2;
    const int EP = E + n;
    const int NB = (n + 63) >> 6;              // buckets (<=1024 for n<=65536)

    char* p = (char*)d_ws;
    auto alloc = [&](size_t bytes) {
        void* q = (void*)p;
        p += (bytes + 255) & ~(size_t)255;
        return q;
    };
    int*   bdeg    = (int*)alloc((size_t)NB * 4);
    int*   bstart  = (int*)alloc((size_t)(NB + 1) * 4);
    int*   bcursor = (int*)alloc((size_t)NB * 4);
    int*   row_ptr = (int*)alloc((size_t)(n + 1) * 4);
    int*   ssrc    = (int*)alloc((size_t)EP * 4);
    // hbuf (bf16 features) aliases the sort's temp array T; size = max of both.
    size_t hbytes = (size_t)n * 64 * 2;
    size_t tbytes = (size_t)EP * 4;
    void*  hraw   = alloc(hbytes > tbytes ? hbytes : tbytes);
    __hip_bfloat16* hbuf = (__hip_bfloat16*)hraw;
    unsigned*       T    = (unsigned*)hraw;    // consumed before first GEMM writes
    float* a_s     = (float*)alloc((size_t)n * 8 * 4);
    float* a_d     = (float*)alloc((size_t)n * 8 * 4);
    float* feat    = (float*)alloc((size_t)n * 64 * 4);
    (void)ws_size;

    hipMemsetAsync(bdeg, 0, (size_t)NB * 4, stream);
    bucket_count<<<256, 256, 0, stream>>>(edges, E, n, NB, bdeg);
    bucket_scan<<<1, 1024, 0, stream>>>(bdeg, bstart, bcursor, row_ptr, NB, n, EP);
    partition<<<(EP + PCHUNK - 1) / PCHUNK, 256, 0, stream>>>(edges, E, n, NB, bcursor, T);
    bucket_sort<<<NB, 256, 0, stream>>>(T, bstart, n, row_ptr, ssrc);

    int gb = (n + 63) / 64;       // gemm blocks
    int ab = (n + 3) / 4;         // aggregate blocks (4 waves/block)

    // Layer 0: 64 -> 8x8, concat, ELU
    gemm_att<64, 8><<<gb, 256, 0, stream>>>(x, W0, as0, ad0, hbuf, a_s, a_d, n);
    aggregate<8, 8, true><<<ab, 256, 0, stream>>>(row_ptr, ssrc, hbuf, a_s, a_d, b0, feat, n);

    // Layer 1: 64 -> 8x8, concat, ELU
    gemm_att<64, 8><<<gb, 256, 0, stream>>>(feat, W1, as1, ad1, hbuf, a_s, a_d, n);
    aggregate<8, 8, true><<<ab, 256, 0, stream>>>(row_ptr, ssrc, hbuf, a_s, a_d, b1, feat, n);

    // Layer 2: 64 -> 1x32, mean(=identity), no ELU
    gemm_att<32, 1><<<gb, 256, 0, stream>>>(feat, W2, as2, ad2, hbuf, a_s, a_d, n);
    aggregate<1, 32, false><<<ab, 256, 0, stream>>>(row_ptr, ssrc, hbuf, a_s, a_d, b2,
                                                    (float*)d_out, n);
}